// Round 2
// baseline (4031.124 us; speedup 1.0000x reference)
//
#include <hip/hip_runtime.h>
#include <cmath>

constexpr int N = 4096;
constexpr int EDG = 131072;
constexpr float GEPS = 1e-6f;

// ---------------------------------------------------------------------------
// OUT[r,f] += sum_{j in chunk} (M[r,j]+eps) * X[j,f]     M row-major NxN.
// thread = (row-quad rw=t>>2 -> 4 rows, j-quad q=t&3). Lanes cover 4KB of M
// per wave-instruction group, fully line-coalesced. X staged in LDS.
template<int FC, int NJ>
__global__ __launch_bounds__(256) void spass(const float* __restrict__ M, float eps,
                                             const float* __restrict__ X,
                                             float* __restrict__ OUT) {
  constexpr int CH = N / NJ;                 // j per block (128 for NJ=32)
  __shared__ float Xt[CH * FC];
  const int t = threadIdx.x;
  const int j0 = blockIdx.y * CH;
  for (int i = t; i < CH * FC / 4; i += 256)
    ((float4*)Xt)[i] = ((const float4*)(X + (size_t)j0 * FC))[i];
  __syncthreads();
  const int q = t & 3;
  const int r0 = blockIdx.x * 256 + (t >> 2) * 4;
  float acc[4][FC];
#pragma unroll
  for (int i = 0; i < 4; ++i)
#pragma unroll
    for (int f = 0; f < FC; ++f) acc[i][f] = 0.f;
  const float* Mp = M + (size_t)r0 * N + j0 + q * 4;
#pragma unroll 2
  for (int k = 0; k < CH / 16; ++k) {
    float4 m[4];
#pragma unroll
    for (int i = 0; i < 4; ++i)
      m[i] = *(const float4*)(Mp + (size_t)i * N + k * 16);
    float me[4][4];
#pragma unroll
    for (int i = 0; i < 4; ++i) {
      me[i][0] = m[i].x + eps; me[i][1] = m[i].y + eps;
      me[i][2] = m[i].z + eps; me[i][3] = m[i].w + eps;
    }
    const float* xr = Xt + (k * 16 + q * 4) * FC;
#pragma unroll
    for (int f = 0; f < FC; ++f) {
      float x0 = xr[f], x1 = xr[FC + f], x2 = xr[2 * FC + f], x3 = xr[3 * FC + f];
#pragma unroll
      for (int i = 0; i < 4; ++i)
        acc[i][f] += me[i][0] * x0 + me[i][1] * x1 + me[i][2] * x2 + me[i][3] * x3;
    }
  }
  // reduce the 4 j-quads (lanes q=0..3 within each quad)
#pragma unroll
  for (int i = 0; i < 4; ++i)
#pragma unroll
    for (int f = 0; f < FC; ++f) {
      acc[i][f] += __shfl_xor(acc[i][f], 1);
      acc[i][f] += __shfl_xor(acc[i][f], 2);
    }
  if (q == 0) {
#pragma unroll
    for (int i = 0; i < 4; ++i)
#pragma unroll
      for (int f = 0; f < FC; ++f)
        atomicAdd(&OUT[(size_t)(r0 + i) * FC + f], acc[i][f]);
  }
}

// OUT[r, 0..63] += sum_j M[r,j]*X[j,0..63]  (conv1; eps=0). thread=(rowquad, fgroup)
template<int NJ>
__global__ __launch_bounds__(256) void cpass64(const float* __restrict__ M,
                                               const float* __restrict__ X,
                                               float* __restrict__ OUT) {
  constexpr int CH = N / NJ;                 // 128
  __shared__ float Xt[32 * 64];              // 8 KB subtile
  const int t = threadIdx.x;
  const int fg = t & 3;
  const int r0 = blockIdx.x * 256 + (t >> 2) * 4;
  const int j0 = blockIdx.y * CH;
  float acc[4][16];
#pragma unroll
  for (int i = 0; i < 4; ++i)
#pragma unroll
    for (int f = 0; f < 16; ++f) acc[i][f] = 0.f;
  for (int sub = 0; sub < CH; sub += 32) {
    __syncthreads();
    for (int i = t; i < 32 * 64 / 4; i += 256)
      ((float4*)Xt)[i] = ((const float4*)(X + (size_t)(j0 + sub) * 64))[i];
    __syncthreads();
    const float* Mp = M + (size_t)r0 * N + j0 + sub;
#pragma unroll
    for (int k = 0; k < 8; ++k) {            // j = sub + 4k .. +3
      float4 m[4];
#pragma unroll
      for (int i = 0; i < 4; ++i)
        m[i] = *(const float4*)(Mp + (size_t)i * N + k * 4);
      const float* xr = Xt + (k * 4) * 64 + fg * 16;
#pragma unroll
      for (int f = 0; f < 16; ++f) {
        float x0 = xr[f], x1 = xr[64 + f], x2 = xr[128 + f], x3 = xr[192 + f];
#pragma unroll
        for (int i = 0; i < 4; ++i)
          acc[i][f] += m[i].x * x0 + m[i].y * x1 + m[i].z * x2 + m[i].w * x3;
      }
    }
  }
#pragma unroll
  for (int i = 0; i < 4; ++i)
#pragma unroll
    for (int f = 0; f < 16; ++f)
      atomicAdd(&OUT[(size_t)(r0 + i) * 64 + fg * 16 + f], acc[i][f]);
}

// ---------------------------------------------------------------------------
// OUT[N,F] = (optional rscale[r] *) A[N,K] @ W[K,F]
template<int F>
__global__ void mm_small(const float* __restrict__ A, const float* __restrict__ W,
                         float* __restrict__ OUT, int K, const float* __restrict__ rscale) {
  constexpr int G = 256 / F;
  constexpr int RPT = 64 / G;
  __shared__ float As[64][33];
  __shared__ float Ws[32][F];
  const int t = threadIdx.x;
  const int f = t & (F - 1);
  const int rg = t / F;
  const int r0 = blockIdx.x * 64;
  float acc[RPT];
#pragma unroll
  for (int i = 0; i < RPT; ++i) acc[i] = 0.f;
  for (int k0 = 0; k0 < K; k0 += 32) {
    for (int idx = t; idx < 64 * 32; idx += 256) {
      int rr = idx >> 5, kk = idx & 31;
      As[rr][kk] = A[(size_t)(r0 + rr) * K + k0 + kk];
    }
    for (int idx = t; idx < 32 * F; idx += 256) {
      int kk = idx / F, ff = idx % F;
      Ws[kk][ff] = W[(size_t)(k0 + kk) * F + ff];
    }
    __syncthreads();
#pragma unroll
    for (int kk = 0; kk < 32; ++kk) {
      float wv = Ws[kk][f];
#pragma unroll
      for (int i = 0; i < RPT; ++i) acc[i] += As[rg * RPT + i][kk] * wv;
    }
    __syncthreads();
  }
#pragma unroll
  for (int i = 0; i < RPT; ++i) {
    int r = r0 + rg * RPT + i;
    float v = acc[i];
    if (rscale) v *= rscale[r];
    OUT[(size_t)r * F + f] = v;
  }
}

// ---------------------------------------------------------------------------
__global__ void edge_gate1(const float* __restrict__ xw, const int* __restrict__ ei,
                           const float* __restrict__ b1, const float* __restrict__ w2,
                           const float* __restrict__ b2, float* __restrict__ s_out,
                           float* __restrict__ D, float* __restrict__ DT,
                           float* __restrict__ deg, float* __restrict__ SCs) {
  const int lane = threadIdx.x & 63;
  const int wave = threadIdx.x >> 6;
  const float b1v = b1[lane];
  const float w2v = w2[lane];
  const float b2s = b2[0];
  float lsum = 0.f, lssq = 0.f;
  for (int it = 0; it < 16; ++it) {
    const int e = blockIdx.x * 64 + it * 4 + wave;
    const int s = ei[e];
    const int d = ei[EDG + e];
    float g = xw[(size_t)s * 64 + lane] - xw[(size_t)d * 64 + lane] + b1v;
    g = fmaxf(g, 0.f) * w2v;
#pragma unroll
    for (int off = 32; off; off >>= 1) g += __shfl_down(g, off);
    if (lane == 0) {
      float agg = g + b2s;
      agg *= agg;
      float sv = 1.f / (1.f + __expf(-agg));
      s_out[e] = sv;
      atomicAdd(&D[(size_t)s * N + d], sv);
      atomicAdd(&DT[(size_t)d * N + s], sv);
      atomicAdd(&deg[d], sv);
      lsum += sv; lssq += sv * sv;
    }
  }
  __shared__ float red[8];
  if (lane == 0) { red[wave] = lsum; red[4 + wave] = lssq; }
  __syncthreads();
  if (threadIdx.x == 0) {
    atomicAdd(&SCs[0], red[0] + red[1] + red[2] + red[3]);
    atomicAdd(&SCs[1], red[4] + red[5] + red[6] + red[7]);
  }
}

__global__ void edge_gate2(const float* __restrict__ xw, const int* __restrict__ ei,
                           const float* __restrict__ b1, const float* __restrict__ w2,
                           const float* __restrict__ b2, float* __restrict__ s_out,
                           float* __restrict__ D, float* __restrict__ DT,
                           float* __restrict__ deg, float* __restrict__ SCs) {
  const int half = threadIdx.x & 31;
  const int wi = threadIdx.x >> 5;   // 0..7 half-waves
  const float b1v = b1[half];
  const float w2v = w2[half];
  const float b2s = b2[0];
  float lsum = 0.f, lssq = 0.f;
  for (int it = 0; it < 16; ++it) {
    const int e = blockIdx.x * 128 + it * 8 + wi;
    const int s = ei[e];
    const int d = ei[EDG + e];
    float g = xw[(size_t)s * 32 + half] - xw[(size_t)d * 32 + half] + b1v;
    g = fmaxf(g, 0.f) * w2v;
#pragma unroll
    for (int off = 16; off; off >>= 1) g += __shfl_down(g, off, 32);
    if (half == 0) {
      float agg = g + b2s;
      agg *= agg;
      float sv = 1.f / (1.f + __expf(-agg));
      s_out[e] = sv;
      atomicAdd(&D[(size_t)s * N + d], sv);
      atomicAdd(&DT[(size_t)d * N + s], sv);
      atomicAdd(&deg[d], sv);
      lsum += sv; lssq += sv * sv;
    }
  }
  __shared__ float red[16];
  if (half == 0) { red[wi] = lsum; red[8 + wi] = lssq; }
  __syncthreads();
  if (threadIdx.x == 0) {
    float a = 0.f, b = 0.f;
    for (int i = 0; i < 8; ++i) { a += red[i]; b += red[8 + i]; }
    atomicAdd(&SCs[0], a);
    atomicAdd(&SCs[1], b);
  }
}

// ---------------------------------------------------------------------------
__global__ void make_dis(const float* __restrict__ deg, float* __restrict__ dis) {
  int n = blockIdx.x * 256 + threadIdx.x;
  dis[n] = rsqrtf(deg[n] + 1.0f);   // +1 self-loop weight
}

// x1 = relu(dis*(P + xh) + bias)   (F=64)
__global__ void conv_epi64(const float* __restrict__ P, const float* __restrict__ xh,
                           const float* __restrict__ dis, const float* __restrict__ bias,
                           float* __restrict__ out) {
  int i = blockIdx.x * 256 + threadIdx.x;
  int n = i >> 6, f = i & 63;
  float v = dis[n] * (P[i] + xh[i]) + bias[f];
  out[i] = fmaxf(v, 0.f);
}

// fused conv2 epilogue + log_softmax/softmax + calib sum
__global__ void conv2_softmax(const float* __restrict__ P, const float* __restrict__ xh,
                              const float* __restrict__ dis, const float* __restrict__ bias,
                              float* __restrict__ ls, float* __restrict__ sm,
                              float* __restrict__ SC) {
  const int t = threadIdx.x;
  const int r = blockIdx.x * 256 + t;
  const float d = dis[r];
  float v[16];
  float mx = -3.0e38f, mx2 = -3.0e38f;
#pragma unroll
  for (int c = 0; c < 16; ++c) {
    v[c] = d * (P[(size_t)r * 16 + c] + xh[(size_t)r * 16 + c]) + bias[c];
    if (v[c] > mx) { mx2 = mx; mx = v[c]; }
    else if (v[c] > mx2) mx2 = v[c];
  }
  float se = 0.f;
#pragma unroll
  for (int c = 0; c < 16; ++c) se += expf(v[c] - mx);
  const float lse = mx + logf(se);
#pragma unroll
  for (int c = 0; c < 16; ++c) {
    float z = v[c] - lse;
    ls[(size_t)r * 16 + c] = z;
    sm[(size_t)r * 16 + c] = expf(z);
  }
  float calib = mx2 - mx;
  const int lane = t & 63, wave = t >> 6;
#pragma unroll
  for (int off = 32; off; off >>= 1) calib += __shfl_down(calib, off);
  __shared__ float red[4];
  if (lane == 0) red[wave] = calib;
  __syncthreads();
  if (t == 0) atomicAdd(&SC[4], red[0] + red[1] + red[2] + red[3]);
}

// ---------------------------------------------------------------------------
// Gram of 6 columns (stride given); optional Cholesky (upper R, G = R^T R)
__global__ void gram6(const float* __restrict__ Y, int stride,
                      double* __restrict__ G, double* __restrict__ R, int do_chol) {
  const int t = threadIdx.x;
  const int lane = t & 63, wave = t >> 6;
  float g[21];
#pragma unroll
  for (int p = 0; p < 21; ++p) g[p] = 0.f;
  for (int n = t; n < N; n += 256) {
    float y[6];
#pragma unroll
    for (int j = 0; j < 6; ++j) y[j] = Y[(size_t)n * stride + j];
    int p = 0;
#pragma unroll
    for (int i = 0; i < 6; ++i)
#pragma unroll
      for (int j = i; j < 6; ++j) g[p++] += y[i] * y[j];
  }
#pragma unroll
  for (int p = 0; p < 21; ++p)
    for (int off = 32; off; off >>= 1) g[p] += __shfl_down(g[p], off);
  __shared__ float part[4][21];
  if (lane == 0)
    for (int p = 0; p < 21; ++p) part[wave][p] = g[p];
  __syncthreads();
  if (t == 0) {
    double Gf[6][6];
    int p = 0;
    for (int i = 0; i < 6; ++i)
      for (int j = i; j < 6; ++j) {
        double val = (double)part[0][p] + part[1][p] + part[2][p] + part[3][p];
        Gf[i][j] = val; Gf[j][i] = val; G[p] = val; ++p;
      }
    if (do_chol) {
      double Rm[6][6];
      for (int i = 0; i < 6; ++i) for (int j = 0; j < 6; ++j) Rm[i][j] = 0.0;
      for (int j = 0; j < 6; ++j) {
        double s = Gf[j][j];
        for (int k = 0; k < j; ++k) s -= Rm[k][j] * Rm[k][j];
        double dj = sqrt(fmax(s, 1e-30));
        Rm[j][j] = dj;
        for (int i = j + 1; i < 6; ++i) {
          double v = Gf[j][i];
          for (int k = 0; k < j; ++k) v -= Rm[k][j] * Rm[k][i];
          Rm[j][i] = v / dj;
        }
      }
      for (int i = 0; i < 6; ++i)
        for (int j = 0; j < 6; ++j) R[i * 6 + j] = Rm[i][j];
    }
  }
}

// Y <- Y * R^{-1} (per row forward substitution)
__global__ void cholqr_apply(float* __restrict__ Y, int stride, const double* __restrict__ R) {
  __shared__ float Rs[36];
  if (threadIdx.x < 36) Rs[threadIdx.x] = (float)R[threadIdx.x];
  __syncthreads();
  int n = blockIdx.x * 256 + threadIdx.x;
  float y[6], q[6];
#pragma unroll
  for (int j = 0; j < 6; ++j) y[j] = Y[(size_t)n * stride + j];
#pragma unroll
  for (int j = 0; j < 6; ++j) {
    float s = y[j];
#pragma unroll
    for (int i = 0; i < 6; ++i)
      if (i < j) s -= q[i] * Rs[i * 6 + j];
    q[j] = s / Rs[j * 6 + j];
  }
#pragma unroll
  for (int j = 0; j < 6; ++j) Y[(size_t)n * stride + j] = q[j];
}

__global__ void jacobi6(const double* __restrict__ G, float* __restrict__ Wm,
                        float* __restrict__ rs) {
  if (threadIdx.x || blockIdx.x) return;
  double A[6][6], V[6][6];
  int p = 0;
  for (int i = 0; i < 6; ++i)
    for (int j = i; j < 6; ++j) { A[i][j] = G[p]; A[j][i] = G[p]; ++p; }
  for (int i = 0; i < 6; ++i)
    for (int j = 0; j < 6; ++j) V[i][j] = (i == j) ? 1.0 : 0.0;
  for (int sweep = 0; sweep < 30; ++sweep) {
    double off = 0.0;
    for (int i = 0; i < 6; ++i)
      for (int j = i + 1; j < 6; ++j) off += A[i][j] * A[i][j];
    if (off < 1e-24) break;
    for (int pi = 0; pi < 5; ++pi)
      for (int qi = pi + 1; qi < 6; ++qi) {
        double apq = A[pi][qi];
        if (fabs(apq) < 1e-300) continue;
        double app = A[pi][pi], aqq = A[qi][qi];
        double tau = (aqq - app) / (2.0 * apq);
        double tt = (tau >= 0.0) ? 1.0 / (tau + sqrt(1.0 + tau * tau))
                                 : 1.0 / (tau - sqrt(1.0 + tau * tau));
        double c = 1.0 / sqrt(1.0 + tt * tt), s = tt * c;
        for (int k = 0; k < 6; ++k) {
          double akp = A[k][pi], akq = A[k][qi];
          A[k][pi] = c * akp - s * akq; A[k][qi] = s * akp + c * akq;
        }
        for (int k = 0; k < 6; ++k) {
          double apk = A[pi][k], aqk = A[qi][k];
          A[pi][k] = c * apk - s * aqk; A[qi][k] = s * apk + c * aqk;
        }
        for (int k = 0; k < 6; ++k) {
          double vkp = V[k][pi], vkq = V[k][qi];
          V[k][pi] = c * vkp - s * vkq; V[k][qi] = s * vkp + c * vkq;
        }
      }
  }
  int idx[6] = {0, 1, 2, 3, 4, 5};
  for (int a = 0; a < 5; ++a)
    for (int b = 0; b < 5 - a; ++b)
      if (A[idx[b]][idx[b]] < A[idx[b + 1]][idx[b + 1]]) {
        int tmp = idx[b]; idx[b] = idx[b + 1]; idx[b + 1] = tmp;
      }
  for (int k = 0; k < 6; ++k) {
    double lam = A[idx[k]][idx[k]];
    rs[k] = (float)(1.0 / sqrt(fmax(lam, 1e-30)));
    for (int j = 0; j < 6; ++j) Wm[j * 6 + k] = (float)V[j][idx[k]];
  }
}

// V8[n,k] = (sum_j Bt[n,j]*Wm[j,k]) * rs[k];  cols 6,7 zeroed
__global__ void v_scale(const float* __restrict__ Bt, const float* __restrict__ Wm,
                        const float* __restrict__ rs, float* __restrict__ V8) {
  __shared__ float Ws[36], rss[6];
  if (threadIdx.x < 36) Ws[threadIdx.x] = Wm[threadIdx.x];
  if (threadIdx.x < 6) rss[threadIdx.x] = rs[threadIdx.x];
  __syncthreads();
  int n = blockIdx.x * 256 + threadIdx.x;
  float b[6];
#pragma unroll
  for (int j = 0; j < 6; ++j) b[j] = Bt[(size_t)n * 8 + j];
#pragma unroll
  for (int k = 0; k < 6; ++k) {
    float s = 0.f;
#pragma unroll
    for (int j = 0; j < 6; ++j) s += b[j] * Ws[j * 6 + k];
    V8[(size_t)n * 8 + k] = s * rss[k];
  }
  V8[(size_t)n * 8 + 6] = 0.f;
  V8[(size_t)n * 8 + 7] = 0.f;
}

__global__ void pad8(const float* __restrict__ src, float* __restrict__ dst) {
  int n = blockIdx.x * 256 + threadIdx.x;
#pragma unroll
  for (int k = 0; k < 6; ++k) dst[(size_t)n * 8 + k] = src[(size_t)n * 6 + k];
  dst[(size_t)n * 8 + 6] = 0.f;
  dst[(size_t)n * 8 + 7] = 0.f;
}

__global__ void pack3(const float* __restrict__ V8, float* __restrict__ W) {
  int n = blockIdx.x * 256 + threadIdx.x;
  W[(size_t)n * 4 + 0] = V8[(size_t)n * 8 + 0];
  W[(size_t)n * 4 + 1] = V8[(size_t)n * 8 + 1];
  W[(size_t)n * 4 + 2] = V8[(size_t)n * 8 + 2];
  W[(size_t)n * 4 + 3] = 0.f;
}

// out[n*FCpad+t] = base[n]*prod_{bit b of t} U[b*N+n], t<nterms; zero pad
__global__ void build_W(float* __restrict__ out, int FCpad, int nterms, int nu,
                        const float* __restrict__ base, int bstride, int boff,
                        const float* __restrict__ U, const float* __restrict__ SC,
                        int rs_idx) {
  int n = blockIdx.x * 256 + threadIdx.x;
  float bv = base[(size_t)n * bstride + boff];
  if (rs_idx >= 0) bv *= rsqrtf(SC[rs_idx]);
  float uv[3];
  for (int b = 0; b < 3; ++b) uv[b] = (b < nu) ? U[(size_t)b * N + n] : 0.f;
  for (int t = 0; t < FCpad; ++t) {
    float v = 0.f;
    if (t < nterms) {
      v = bv;
      for (int b = 0; b < nu; ++b)
        if ((t >> b) & 1) v *= uv[b];
    }
    out[(size_t)n * FCpad + t] = v;
  }
}

// y[n] = sum_t (-1)^popc(t) * (prod_{b in t} U_b[n]) * Y[n*FCpad+t]
__global__ void combine_y(float* __restrict__ y, const float* __restrict__ Y,
                          int FCpad, int nterms, int nu, const float* __restrict__ U) {
  int n = blockIdx.x * 256 + threadIdx.x;
  float uv[3];
  for (int b = 0; b < 3; ++b) uv[b] = (b < nu) ? U[(size_t)b * N + n] : 0.f;
  float s = 0.f;
  for (int t = 0; t < nterms; ++t) {
    float w = Y[(size_t)n * FCpad + t];
    int pc = 0;
    for (int b = 0; b < nu; ++b)
      if ((t >> b) & 1) { w *= uv[b]; ++pc; }
    s += (pc & 1) ? -w : w;
  }
  y[n] = s;
}

__global__ void cols_sumsq(const float* __restrict__ X, int stride, int ncols,
                           float* __restrict__ SC, int idx0) {
  const int t = threadIdx.x;
  const int lane = t & 63, wave = t >> 6;
  const int n = blockIdx.x * 256 + t;
  float a[8];
#pragma unroll
  for (int c = 0; c < 8; ++c) a[c] = 0.f;
  for (int c = 0; c < ncols; ++c) {
    float v = X[(size_t)n * stride + c];
    a[c] = v * v;
  }
  for (int c = 0; c < ncols; ++c)
    for (int off = 32; off; off >>= 1) a[c] += __shfl_down(a[c], off);
  __shared__ float part[4][8];
  if (lane == 0)
    for (int c = 0; c < ncols; ++c) part[wave][c] = a[c];
  __syncthreads();
  if (t == 0)
    for (int c = 0; c < ncols; ++c)
      atomicAdd(&SC[idx0 + c], part[0][c] + part[1][c] + part[2][c] + part[3][c]);
}

__global__ void vec_dot(const float* __restrict__ A, int sa, int oa,
                        const float* __restrict__ B, int sb, int ob,
                        float* __restrict__ SC, int idx) {
  const int t = threadIdx.x;
  const int lane = t & 63, wave = t >> 6;
  const int n = blockIdx.x * 256 + t;
  float v = A[(size_t)n * sa + oa] * B[(size_t)n * sb + ob];
  for (int off = 32; off; off >>= 1) v += __shfl_down(v, off);
  __shared__ float part[4];
  if (lane == 0) part[wave] = v;
  __syncthreads();
  if (t == 0) atomicAdd(&SC[idx], part[0] + part[1] + part[2] + part[3]);
}

__global__ void vscale1(float* __restrict__ out, const float* __restrict__ in,
                        int stride, int off, const float* __restrict__ SC, int rs_idx) {
  int n = blockIdx.x * 256 + threadIdx.x;
  float v = in[(size_t)n * stride + off];
  if (rs_idx >= 0) v *= rsqrtf(SC[rs_idx]);
  out[n] = v;
}

__global__ void axpy3(float* __restrict__ out, const float* __restrict__ Y, int stride,
                      int off, const float* __restrict__ q0, const float* __restrict__ q1,
                      const float* __restrict__ q2, const float* __restrict__ SC,
                      int c0, int c1, int c2, int np, int coef_rs, int out_rs) {
  int n = blockIdx.x * 256 + threadIdx.x;
  float crs = (coef_rs >= 0) ? rsqrtf(SC[coef_rs]) : 1.f;
  float s = Y[(size_t)n * stride + off];
  if (np > 0) s -= SC[c0] * crs * q0[n];
  if (np > 1) s -= SC[c1] * crs * q1[n];
  if (np > 2) s -= SC[c2] * crs * q2[n];
  if (out_rs >= 0) s *= rsqrtf(SC[out_rs]);
  out[n] = s;
}

__global__ void nuc_accum(float* __restrict__ SC, int mode, int z0, int nterms,
                          int ny0, int dps, int nd) {
  if (threadIdx.x || blockIdx.x) return;
  float add = 0.f;
  if (mode == 0) {
    for (int k = 0; k < 3; ++k) add += sqrtf(fabsf(SC[z0 + k] / SC[ny0 + k]));
  } else if (mode == 1) {
    float vmv = 0.f;
    for (int t = 0; t < nterms; ++t) {
      int pc = __popc(t);
      vmv += (pc & 1) ? -SC[z0 + t] : SC[z0 + t];
    }
    add = sqrtf(fabsf(vmv / SC[ny0]));
  } else {
    float vmv = SC[z0];
    for (int t = 0; t < nd; ++t) vmv -= SC[dps + 2 * t] * SC[dps + 2 * t + 1];
    add = sqrtf(fabsf(vmv / SC[ny0]));
  }
  SC[5] += add;
}

__global__ void finalize_k(const float* __restrict__ SC, float* __restrict__ out) {
  if (threadIdx.x || blockIdx.x) return;
  const float Ef = (float)EDG;
  float m1 = SC[0] / Ef, v1 = SC[1] / Ef - m1 * m1;
  float m2 = SC[2] / Ef, v2 = SC[3] / Ef - m2 * m2;
  out[131072] = 0.01f * (v1 + v2) + 0.01f * SC[5];
  out[393217] = SC[4] / (float)N;
}

// ---------------------------------------------------------------------------
extern "C" void kernel_launch(void* const* d_in, const int* in_sizes, int n_in,
                              void* d_out, int out_size, void* d_ws, size_t ws_size,
                              hipStream_t stream) {
  const float* x      = (const float*)d_in[0];
  const int*   ei     = (const int*)  d_in[1];
  const float* gcn1_w = (const float*)d_in[2];
  const float* gcn1_b = (const float*)d_in[3];
  const float* gcn2_w = (const float*)d_in[4];
  const float* gcn2_b = (const float*)d_in[5];
  const float* p1w1   = (const float*)d_in[6];
  const float* p1b1   = (const float*)d_in[7];
  const float* p1w2   = (const float*)d_in[8];
  const float* p1b2   = (const float*)d_in[9];
  const float* p2w1   = (const float*)d_in[10];
  const float* p2b1   = (const float*)d_in[11];
  const float* p2w2   = (const float*)d_in[12];
  const float* p2b2   = (const float*)d_in[13];
  const float* omega1 = (const float*)d_in[14];
  const float* omega2 = (const float*)d_in[15];
  float* out = (float*)d_out;

  float* ws = (float*)d_ws;
  size_t o = 0;
  auto alloc = [&](size_t nf) { float* p = ws + o; o += nf; return p; };
  float* D    = alloc((size_t)N * N);
  float* DT   = alloc((size_t)N * N);
  float* xw1  = alloc((size_t)N * 64);
  float* xh   = alloc((size_t)N * 64);
  float* x1   = alloc((size_t)N * 64);
  float* P    = alloc((size_t)N * 64);
  float* x1w  = alloc((size_t)N * 32);
  float* xh2  = alloc((size_t)N * 16);
  float* deg1 = alloc(N);
  float* dis1 = alloc(N);
  float* deg2 = alloc(N);
  float* dis2 = alloc(N);
  float* Qb8  = alloc((size_t)N * 8);
  float* Zi8  = alloc((size_t)N * 8);
  float* Bt8  = alloc((size_t)N * 8);
  float* V8   = alloc((size_t)N * 8);
  float* W8   = alloc((size_t)N * 8);
  float* T8   = alloc((size_t)N * 8);
  float* Y8   = alloc((size_t)N * 8);
  float* Zz8  = alloc((size_t)N * 8);
  float* P8   = alloc((size_t)N * 8);
  float* yv   = alloc(N);
  float* Uv   = alloc((size_t)3 * N);
  float* Pv   = alloc((size_t)3 * N);
  float* SC   = alloc(256);
  float* SMF  = alloc(64);            // Wm[36] + rs[6]
  o = (o + 1) & ~(size_t)1;
  double* Gd = (double*)(ws + o); o += 48;   // 21 doubles (padded)
  double* Rd = (double*)(ws + o); o += 80;   // 36 doubles (padded)
  if (ws_size < o * sizeof(float)) return;   // insufficient scratch -> loud failure

  auto zero = [&](float* p, size_t nf) {
    hipMemsetAsync(p, 0, nf * sizeof(float), stream);
  };

  // SC slots
  enum {
    A_NY = 8,  A_Z = 11,
    A_NY3 = 14, A_Z3 = 15,
    A_NY4 = 17, A_Z4 = 18,
    A_NY5 = 22, A_Z5 = 23,
    B_NY = 34, B_Z = 37,
    B_C3 = 40, B_NY3 = 41, B_ZZ3 = 42, B_DP3 = 43,
    B_C4 = 45, B_NY4 = 47, B_ZZ4 = 48, B_DP4 = 49,
    B_C5 = 53, B_NY5 = 56, B_ZZ5 = 57, B_DP5 = 58
  };

  const dim3 PG(16, 32);   // spass grid: 256 rows x 128-j chunks

  auto run_svd = [&](const float* omega) {
    pad8<<<16, 256, 0, stream>>>(omega, W8);
    zero(Qb8, (size_t)N * 8);
    spass<8, 32><<<PG, 256, 0, stream>>>(D, GEPS, W8, Qb8);
    gram6<<<1, 256, 0, stream>>>(Qb8, 8, Gd, Rd, 1);
    cholqr_apply<<<16, 256, 0, stream>>>(Qb8, 8, Rd);
    for (int itp = 0; itp < 2; ++itp) {
      zero(Zi8, (size_t)N * 8);
      spass<8, 32><<<PG, 256, 0, stream>>>(DT, GEPS, Qb8, Zi8);
      gram6<<<1, 256, 0, stream>>>(Zi8, 8, Gd, Rd, 1);
      cholqr_apply<<<16, 256, 0, stream>>>(Zi8, 8, Rd);
      zero(Qb8, (size_t)N * 8);
      spass<8, 32><<<PG, 256, 0, stream>>>(D, GEPS, Zi8, Qb8);
      gram6<<<1, 256, 0, stream>>>(Qb8, 8, Gd, Rd, 1);
      cholqr_apply<<<16, 256, 0, stream>>>(Qb8, 8, Rd);
    }
    zero(Bt8, (size_t)N * 8);
    spass<8, 32><<<PG, 256, 0, stream>>>(DT, GEPS, Qb8, Bt8);
    gram6<<<1, 256, 0, stream>>>(Bt8, 8, Gd, nullptr, 0);
    jacobi6<<<1, 1, 0, stream>>>(Gd, SMF, SMF + 36);
    v_scale<<<16, 256, 0, stream>>>(Bt8, SMF, SMF + 36, V8);
  };

  auto nuc_batch3 = [&](int nyIdx, int zIdx) {
    pack3<<<16, 256, 0, stream>>>(V8, W8);
    zero(T8, (size_t)N * 4);
    spass<4, 32><<<PG, 256, 0, stream>>>(DT, GEPS, W8, T8);
    zero(Y8, (size_t)N * 4);
    spass<4, 32><<<PG, 256, 0, stream>>>(D, GEPS, T8, Y8);
    cols_sumsq<<<16, 256, 0, stream>>>(Y8, 4, 3, SC, nyIdx);
    zero(Zz8, (size_t)N * 4);
    spass<4, 32><<<PG, 256, 0, stream>>>(DT, GEPS, Y8, Zz8);
    cols_sumsq<<<16, 256, 0, stream>>>(Zz8, 4, 3, SC, zIdx);
    nuc_accum<<<1, 1, 0, stream>>>(SC, 0, zIdx, 3, nyIdx, 0, 0);
    vscale1<<<16, 256, 0, stream>>>(Uv, Y8, 4, 2, SC, nyIdx + 2);  // u2
  };

  // ===================== init =====================
  zero(D, (size_t)N * N);
  zero(DT, (size_t)N * N);
  zero(deg1, N);
  zero(deg2, N);
  zero(SC, 256);

  // ===================== graph 1: gate + conv =====================
  mm_small<64><<<64, 256, 0, stream>>>(x, p1w1, xw1, 512, nullptr);
  edge_gate1<<<2048, 256, 0, stream>>>(xw1, ei, p1b1, p1w2, p1b2,
                                       out + 131073, D, DT, deg1, SC + 0);
  make_dis<<<16, 256, 0, stream>>>(deg1, dis1);
  mm_small<64><<<64, 256, 0, stream>>>(x, gcn1_w, xh, 512, dis1);  // xh = dis*h
  zero(P, (size_t)N * 64);
  cpass64<32><<<PG, 256, 0, stream>>>(DT, xh, P);
  conv_epi64<<<1024, 256, 0, stream>>>(P, xh, dis1, gcn1_b, x1);

  // ===================== SVD1 + nuc1 (elementwise deflation) =====================
  run_svd(omega1);
  nuc_batch3(A_NY, A_Z);
  {
    const int NYk[3] = {A_NY3, A_NY4, A_NY5};
    const int Zk[3]  = {A_Z3, A_Z4, A_Z5};
    for (int k = 3; k <= 5; ++k) {
      int nu = k - 2, nt = 1 << nu;
      int ny = NYk[k - 3], zz = Zk[k - 3];
      if (k < 5) {
        build_W<<<16, 256, 0, stream>>>(W8, 4, nt, nu, V8, 8, k, Uv, SC, -1);
        zero(T8, (size_t)N * 4);
        spass<4, 32><<<PG, 256, 0, stream>>>(DT, GEPS, W8, T8);
        zero(Y8, (size_t)N * 4);
        spass<4, 32><<<PG, 256, 0, stream>>>(D, GEPS, T8, Y8);
        combine_y<<<16, 256, 0, stream>>>(yv, Y8, 4, nt, nu, Uv);
        cols_sumsq<<<16, 256, 0, stream>>>(yv, 1, 1, SC, ny);
        build_W<<<16, 256, 0, stream>>>(W8, 4, nt, nu, yv, 1, 0, Uv, SC, -1);
        zero(Zz8, (size_t)N * 4);
        spass<4, 32><<<PG, 256, 0, stream>>>(DT, GEPS, W8, Zz8);
        cols_sumsq<<<16, 256, 0, stream>>>(Zz8, 4, nt, SC, zz);
      } else {
        build_W<<<16, 256, 0, stream>>>(W8, 8, nt, nu, V8, 8, k, Uv, SC, -1);
        zero(T8, (size_t)N * 8);
        spass<8, 32><<<PG, 256, 0, stream>>>(DT, GEPS, W8, T8);
        zero(Y8, (size_t)N * 8);
        spass<8, 32><<<PG, 256, 0, stream>>>(D, GEPS, T8, Y8);
        combine_y<<<16, 256, 0, stream>>>(yv, Y8, 8, nt, nu, Uv);
        cols_sumsq<<<16, 256, 0, stream>>>(yv, 1, 1, SC, ny);
        build_W<<<16, 256, 0, stream>>>(W8, 8, nt, nu, yv, 1, 0, Uv, SC, -1);
        zero(Zz8, (size_t)N * 8);
        spass<8, 32><<<PG, 256, 0, stream>>>(DT, GEPS, W8, Zz8);
        cols_sumsq<<<16, 256, 0, stream>>>(Zz8, 8, nt, SC, zz);
      }
      nuc_accum<<<1, 1, 0, stream>>>(SC, 1, zz, nt, ny, 0, 0);
      if (k < 5)
        vscale1<<<16, 256, 0, stream>>>(Uv + (size_t)(k - 2) * N, yv, 1, 0, SC, ny);
    }
  }

  // ===================== graph 2: gate + conv + outputs =====================
  zero(D, (size_t)N * N);
  zero(DT, (size_t)N * N);
  mm_small<32><<<64, 256, 0, stream>>>(x1, p2w1, x1w, 64, nullptr);
  edge_gate2<<<1024, 256, 0, stream>>>(x1w, ei, p2b1, p2w2, p2b2,
                                       out + 262145, D, DT, deg2, SC + 2);
  make_dis<<<16, 256, 0, stream>>>(deg2, dis2);
  mm_small<16><<<64, 256, 0, stream>>>(x1, gcn2_w, xh2, 64, dis2);  // xh2 = dis*h
  zero(P, (size_t)N * 16);
  spass<16, 32><<<PG, 256, 0, stream>>>(DT, 0.f, xh2, P);
  conv2_softmax<<<16, 256, 0, stream>>>(P, xh2, dis2, gcn2_b, out, out + 65536, SC);

  // ===================== SVD2 + nuc2 (rank-1 deflation) =====================
  run_svd(omega2);
  nuc_batch3(B_NY, B_Z);
  // p2 = A @ (Z col2 * rsqrt(ny2))
  build_W<<<16, 256, 0, stream>>>(W8, 4, 1, 0, Zz8, 4, 2, nullptr, SC, B_NY + 2);
  zero(P8, (size_t)N * 4);
  spass<4, 32><<<PG, 256, 0, stream>>>(D, GEPS, W8, P8);
  vscale1<<<16, 256, 0, stream>>>(Pv, P8, 4, 0, SC, -1);
  {
    const int Ck[3]  = {B_C3, B_C4, B_C5};
    const int NYk[3] = {B_NY3, B_NY4, B_NY5};
    const int ZZk[3] = {B_ZZ3, B_ZZ4, B_ZZ5};
    const int DPk[3] = {B_DP3, B_DP4, B_DP5};
    for (int k = 3; k <= 5; ++k) {
      int nd = k - 2;
      int C = Ck[k - 3], ny = NYk[k - 3], zz = ZZk[k - 3], dp = DPk[k - 3];
      for (int t = 0; t < nd; ++t)
        vec_dot<<<16, 256, 0, stream>>>(Uv + (size_t)t * N, 1, 0, V8, 8, k, SC, C + t);
      build_W<<<16, 256, 0, stream>>>(W8, 4, 1, 0, V8, 8, k, nullptr, SC, -1);
      zero(T8, (size_t)N * 4);
      spass<4, 32><<<PG, 256, 0, stream>>>(DT, GEPS, W8, T8);
      zero(Y8, (size_t)N * 4);
      spass<4, 32><<<PG, 256, 0, stream>>>(D, GEPS, T8, Y8);
      axpy3<<<16, 256, 0, stream>>>(yv, Y8, 4, 0, Pv, Pv + N, Pv + 2 * N,
                                    SC, C, C + 1, C + 2, nd, -1, -1);
      cols_sumsq<<<16, 256, 0, stream>>>(yv, 1, 1, SC, ny);
      build_W<<<16, 256, 0, stream>>>(W8, 4, 1, 0, yv, 1, 0, nullptr, SC, -1);
      zero(Zz8, (size_t)N * 4);
      spass<4, 32><<<PG, 256, 0, stream>>>(DT, GEPS, W8, Zz8);
      cols_sumsq<<<16, 256, 0, stream>>>(Zz8, 4, 1, SC, zz);
      for (int t = 0; t < nd; ++t) {
        vec_dot<<<16, 256, 0, stream>>>(yv, 1, 0, Pv + (size_t)t * N, 1, 0, SC, dp + 2 * t);
        vec_dot<<<16, 256, 0, stream>>>(Uv + (size_t)t * N, 1, 0, yv, 1, 0, SC, dp + 2 * t + 1);
      }
      nuc_accum<<<1, 1, 0, stream>>>(SC, 2, zz, 0, ny, dp, nd);
      if (k < 5) {
        vscale1<<<16, 256, 0, stream>>>(Uv + (size_t)(k - 2) * N, yv, 1, 0, SC, ny);
        build_W<<<16, 256, 0, stream>>>(W8, 4, 1, 0, Zz8, 4, 0, nullptr, SC, ny);
        zero(P8, (size_t)N * 4);
        spass<4, 32><<<PG, 256, 0, stream>>>(D, GEPS, W8, P8);
        axpy3<<<16, 256, 0, stream>>>(Pv + (size_t)(k - 2) * N, P8, 4, 0,
                                      Pv, Pv + N, Pv + 2 * N,
                                      SC, dp + 1, dp + 3, dp + 5, nd, ny, -1);
      }
    }
  }

  finalize_k<<<1, 1, 0, stream>>>(SC, out);
}

// Round 3
// 2364.712 us; speedup vs baseline: 1.7047x; 1.7047x over previous
//
#include <hip/hip_runtime.h>
#include <cmath>

constexpr int N = 4096;
constexpr int EDG = 131072;
constexpr float GEPS = 1e-6f;

// ---------------------------------------------------------------------------
// Sparse adjacency infrastructure. A[s,d] = sum of gate weights over edges
// (s,d). A + eps*ones is applied as SpMM + eps*colsum rank-1 correction.
__global__ void hist_edges(const int* __restrict__ ei, int* __restrict__ cnt) {
  int e = blockIdx.x * 256 + threadIdx.x;
  atomicAdd(&cnt[ei[e]], 1);            // by src
  atomicAdd(&cnt[N + ei[EDG + e]], 1);  // by dst
}

__global__ __launch_bounds__(256) void scan2x(const int* __restrict__ cnt,
                                              int* __restrict__ rowptr,
                                              int* __restrict__ cur) {
  const int b = blockIdx.x;            // 0=src, 1=dst
  const int* c = cnt + b * N;
  int* rp = rowptr + b * (N + 1);
  int* cu = cur + b * N;
  __shared__ int part[256];
  const int t = threadIdx.x;
  int local[16], s = 0;
  const int base = t * 16;
  for (int i = 0; i < 16; ++i) { local[i] = s; s += c[base + i]; }
  part[t] = s;
  __syncthreads();
  if (t == 0) {
    int acc = 0;
    for (int i = 0; i < 256; ++i) { int v = part[i]; part[i] = acc; acc += v; }
  }
  __syncthreads();
  const int off = part[t];
  for (int i = 0; i < 16; ++i) { rp[base + i] = off + local[i]; cu[base + i] = off + local[i]; }
  if (t == 255) rp[N] = off + s;
}

__global__ void scatter_edges(const int* __restrict__ ei, int* __restrict__ cur,
                              int* __restrict__ col_s, int* __restrict__ perm_s,
                              int* __restrict__ col_d, int* __restrict__ perm_d) {
  int e = blockIdx.x * 256 + threadIdx.x;
  int s = ei[e], d = ei[EDG + e];
  int ps = atomicAdd(&cur[s], 1);
  col_s[ps] = d; perm_s[ps] = e;
  int pd = atomicAdd(&cur[N + d], 1);
  col_d[pd] = s; perm_d[pd] = e;
}

__global__ void gather_w2(const float* __restrict__ s, const int* __restrict__ perm_s,
                          const int* __restrict__ perm_d, float* __restrict__ ws_,
                          float* __restrict__ wd_) {
  int p = blockIdx.x * 256 + threadIdx.x;
  ws_[p] = s[perm_s[p]];
  wd_[p] = s[perm_d[p]];
}

// OUT[r,f] = sum_{e in row r} w[e]*X[col[e],f]  (+ eps*colsum[f] if EPSC)
template<int F, int EPSC>
__global__ __launch_bounds__(256) void spmm(const int* __restrict__ rowptr,
                                            const int* __restrict__ col,
                                            const float* __restrict__ w,
                                            const float* __restrict__ X,
                                            float* __restrict__ OUT, float eps) {
  float epsadd = 0.f;
  if (EPSC) {
    __shared__ float part[256];
    float s = 0.f;
    for (int i = threadIdx.x; i < N * F; i += 256) s += X[i];
    part[threadIdx.x] = s;
    __syncthreads();
    float tot = 0.f;
    for (int j = threadIdx.x % F; j < 256; j += F) tot += part[j];
    epsadd = eps * tot;
  }
  constexpr int SL = 64 / F;
  const int lane = threadIdx.x & 63;
  const int wv = threadIdx.x >> 6;
  const int f = lane % F;
  const int slot = lane / F;
  const int r = (blockIdx.x * 4 + wv) * SL + slot;
  const int e0 = rowptr[r], e1 = rowptr[r + 1];
  float acc = 0.f;
  for (int e = e0; e < e1; ++e)
    acc += w[e] * X[(size_t)col[e] * F + f];
  OUT[(size_t)r * F + f] = acc + epsadd;
}

// ---------------------------------------------------------------------------
// OUT[N,F] = (optional rscale[r] *) A[N,K] @ W[K,F]
template<int F>
__global__ void mm_small(const float* __restrict__ A, const float* __restrict__ W,
                         float* __restrict__ OUT, int K, const float* __restrict__ rscale) {
  constexpr int G = 256 / F;
  constexpr int RPT = 64 / G;
  __shared__ float As[64][33];
  __shared__ float Ws[32][F];
  const int t = threadIdx.x;
  const int f = t & (F - 1);
  const int rg = t / F;
  const int r0 = blockIdx.x * 64;
  float acc[RPT];
#pragma unroll
  for (int i = 0; i < RPT; ++i) acc[i] = 0.f;
  for (int k0 = 0; k0 < K; k0 += 32) {
    for (int idx = t; idx < 64 * 32; idx += 256) {
      int rr = idx >> 5, kk = idx & 31;
      As[rr][kk] = A[(size_t)(r0 + rr) * K + k0 + kk];
    }
    for (int idx = t; idx < 32 * F; idx += 256) {
      int kk = idx / F, ff = idx % F;
      Ws[kk][ff] = W[(size_t)(k0 + kk) * F + ff];
    }
    __syncthreads();
#pragma unroll
    for (int kk = 0; kk < 32; ++kk) {
      float wv = Ws[kk][f];
#pragma unroll
      for (int i = 0; i < RPT; ++i) acc[i] += As[rg * RPT + i][kk] * wv;
    }
    __syncthreads();
  }
#pragma unroll
  for (int i = 0; i < RPT; ++i) {
    int r = r0 + rg * RPT + i;
    float v = acc[i];
    if (rscale) v *= rscale[r];
    OUT[(size_t)r * F + f] = v;
  }
}

// ---------------------------------------------------------------------------
__global__ void edge_gate1(const float* __restrict__ xw, const int* __restrict__ ei,
                           const float* __restrict__ b1, const float* __restrict__ w2,
                           const float* __restrict__ b2, float* __restrict__ s_out,
                           float* __restrict__ deg, float* __restrict__ SCs) {
  const int lane = threadIdx.x & 63;
  const int wave = threadIdx.x >> 6;
  const float b1v = b1[lane];
  const float w2v = w2[lane];
  const float b2s = b2[0];
  float lsum = 0.f, lssq = 0.f;
  for (int it = 0; it < 16; ++it) {
    const int e = blockIdx.x * 64 + it * 4 + wave;
    const int s = ei[e];
    const int d = ei[EDG + e];
    float g = xw[(size_t)s * 64 + lane] - xw[(size_t)d * 64 + lane] + b1v;
    g = fmaxf(g, 0.f) * w2v;
#pragma unroll
    for (int off = 32; off; off >>= 1) g += __shfl_down(g, off);
    if (lane == 0) {
      float agg = g + b2s;
      agg *= agg;
      float sv = 1.f / (1.f + __expf(-agg));
      s_out[e] = sv;
      atomicAdd(&deg[d], sv);
      lsum += sv; lssq += sv * sv;
    }
  }
  __shared__ float red[8];
  if (lane == 0) { red[wave] = lsum; red[4 + wave] = lssq; }
  __syncthreads();
  if (threadIdx.x == 0) {
    atomicAdd(&SCs[0], red[0] + red[1] + red[2] + red[3]);
    atomicAdd(&SCs[1], red[4] + red[5] + red[6] + red[7]);
  }
}

__global__ void edge_gate2(const float* __restrict__ xw, const int* __restrict__ ei,
                           const float* __restrict__ b1, const float* __restrict__ w2,
                           const float* __restrict__ b2, float* __restrict__ s_out,
                           float* __restrict__ deg, float* __restrict__ SCs) {
  const int half = threadIdx.x & 31;
  const int wi = threadIdx.x >> 5;   // 0..7 half-waves
  const float b1v = b1[half];
  const float w2v = w2[half];
  const float b2s = b2[0];
  float lsum = 0.f, lssq = 0.f;
  for (int it = 0; it < 16; ++it) {
    const int e = blockIdx.x * 128 + it * 8 + wi;
    const int s = ei[e];
    const int d = ei[EDG + e];
    float g = xw[(size_t)s * 32 + half] - xw[(size_t)d * 32 + half] + b1v;
    g = fmaxf(g, 0.f) * w2v;
#pragma unroll
    for (int off = 16; off; off >>= 1) g += __shfl_down(g, off, 32);
    if (half == 0) {
      float agg = g + b2s;
      agg *= agg;
      float sv = 1.f / (1.f + __expf(-agg));
      s_out[e] = sv;
      atomicAdd(&deg[d], sv);
      lsum += sv; lssq += sv * sv;
    }
  }
  __shared__ float red[16];
  if (half == 0) { red[wi] = lsum; red[8 + wi] = lssq; }
  __syncthreads();
  if (threadIdx.x == 0) {
    float a = 0.f, b = 0.f;
    for (int i = 0; i < 8; ++i) { a += red[i]; b += red[8 + i]; }
    atomicAdd(&SCs[0], a);
    atomicAdd(&SCs[1], b);
  }
}

// ---------------------------------------------------------------------------
__global__ void make_dis(const float* __restrict__ deg, float* __restrict__ dis) {
  int n = blockIdx.x * 256 + threadIdx.x;
  dis[n] = rsqrtf(deg[n] + 1.0f);   // +1 self-loop weight
}

// x1 = relu(dis*(P + xh) + bias)   (F=64; xh = dis*h so dis*xh = dis^2*h)
__global__ void conv_epi64(const float* __restrict__ P, const float* __restrict__ xh,
                           const float* __restrict__ dis, const float* __restrict__ bias,
                           float* __restrict__ out) {
  int i = blockIdx.x * 256 + threadIdx.x;
  int n = i >> 6, f = i & 63;
  float v = dis[n] * (P[i] + xh[i]) + bias[f];
  out[i] = fmaxf(v, 0.f);
}

// fused conv2 epilogue + log_softmax/softmax + calib sum
__global__ void conv2_softmax(const float* __restrict__ P, const float* __restrict__ xh,
                              const float* __restrict__ dis, const float* __restrict__ bias,
                              float* __restrict__ ls, float* __restrict__ sm,
                              float* __restrict__ SC) {
  const int t = threadIdx.x;
  const int r = blockIdx.x * 256 + t;
  const float d = dis[r];
  float v[16];
  float mx = -3.0e38f, mx2 = -3.0e38f;
#pragma unroll
  for (int c = 0; c < 16; ++c) {
    v[c] = d * (P[(size_t)r * 16 + c] + xh[(size_t)r * 16 + c]) + bias[c];
    if (v[c] > mx) { mx2 = mx; mx = v[c]; }
    else if (v[c] > mx2) mx2 = v[c];
  }
  float se = 0.f;
#pragma unroll
  for (int c = 0; c < 16; ++c) se += expf(v[c] - mx);
  const float lse = mx + logf(se);
#pragma unroll
  for (int c = 0; c < 16; ++c) {
    float z = v[c] - lse;
    ls[(size_t)r * 16 + c] = z;
    sm[(size_t)r * 16 + c] = expf(z);
  }
  float calib = mx2 - mx;
  const int lane = t & 63, wave = t >> 6;
#pragma unroll
  for (int off = 32; off; off >>= 1) calib += __shfl_down(calib, off);
  __shared__ float red[4];
  if (lane == 0) red[wave] = calib;
  __syncthreads();
  if (t == 0) atomicAdd(&SC[4], red[0] + red[1] + red[2] + red[3]);
}

// ---------------------------------------------------------------------------
// Gram of 6 columns (stride given); optional Cholesky (upper R, G = R^T R)
__global__ void gram6(const float* __restrict__ Y, int stride,
                      double* __restrict__ G, double* __restrict__ R, int do_chol) {
  const int t = threadIdx.x;
  const int lane = t & 63, wave = t >> 6;
  float g[21];
#pragma unroll
  for (int p = 0; p < 21; ++p) g[p] = 0.f;
  for (int n = t; n < N; n += 256) {
    float y[6];
#pragma unroll
    for (int j = 0; j < 6; ++j) y[j] = Y[(size_t)n * stride + j];
    int p = 0;
#pragma unroll
    for (int i = 0; i < 6; ++i)
#pragma unroll
      for (int j = i; j < 6; ++j) g[p++] += y[i] * y[j];
  }
#pragma unroll
  for (int p = 0; p < 21; ++p)
    for (int off = 32; off; off >>= 1) g[p] += __shfl_down(g[p], off);
  __shared__ float part[4][21];
  if (lane == 0)
    for (int p = 0; p < 21; ++p) part[wave][p] = g[p];
  __syncthreads();
  if (t == 0) {
    double Gf[6][6];
    int p = 0;
    for (int i = 0; i < 6; ++i)
      for (int j = i; j < 6; ++j) {
        double val = (double)part[0][p] + part[1][p] + part[2][p] + part[3][p];
        Gf[i][j] = val; Gf[j][i] = val; G[p] = val; ++p;
      }
    if (do_chol) {
      double Rm[6][6];
      for (int i = 0; i < 6; ++i) for (int j = 0; j < 6; ++j) Rm[i][j] = 0.0;
      for (int j = 0; j < 6; ++j) {
        double s = Gf[j][j];
        for (int k = 0; k < j; ++k) s -= Rm[k][j] * Rm[k][j];
        double dj = sqrt(fmax(s, 1e-30));
        Rm[j][j] = dj;
        for (int i = j + 1; i < 6; ++i) {
          double v = Gf[j][i];
          for (int k = 0; k < j; ++k) v -= Rm[k][j] * Rm[k][i];
          Rm[j][i] = v / dj;
        }
      }
      for (int i = 0; i < 6; ++i)
        for (int j = 0; j < 6; ++j) R[i * 6 + j] = Rm[i][j];
    }
  }
}

// Y <- Y * R^{-1} (per row forward substitution)
__global__ void cholqr_apply(float* __restrict__ Y, int stride, const double* __restrict__ R) {
  __shared__ float Rs[36];
  if (threadIdx.x < 36) Rs[threadIdx.x] = (float)R[threadIdx.x];
  __syncthreads();
  int n = blockIdx.x * 256 + threadIdx.x;
  float y[6], q[6];
#pragma unroll
  for (int j = 0; j < 6; ++j) y[j] = Y[(size_t)n * stride + j];
#pragma unroll
  for (int j = 0; j < 6; ++j) {
    float s = y[j];
#pragma unroll
    for (int i = 0; i < 6; ++i)
      if (i < j) s -= q[i] * Rs[i * 6 + j];
    q[j] = s / Rs[j * 6 + j];
  }
#pragma unroll
  for (int j = 0; j < 6; ++j) Y[(size_t)n * stride + j] = q[j];
}

__global__ void jacobi6(const double* __restrict__ G, float* __restrict__ Wm,
                        float* __restrict__ rs) {
  if (threadIdx.x || blockIdx.x) return;
  double A[6][6], V[6][6];
  int p = 0;
  for (int i = 0; i < 6; ++i)
    for (int j = i; j < 6; ++j) { A[i][j] = G[p]; A[j][i] = G[p]; ++p; }
  double tr = 0.0;
  for (int i = 0; i < 6; ++i) tr += fabs(A[i][i]);
  const double tol = 1e-26 * tr * tr + 1e-300;
  for (int i = 0; i < 6; ++i)
    for (int j = 0; j < 6; ++j) V[i][j] = (i == j) ? 1.0 : 0.0;
  for (int sweep = 0; sweep < 12; ++sweep) {
    double off = 0.0;
    for (int i = 0; i < 6; ++i)
      for (int j = i + 1; j < 6; ++j) off += A[i][j] * A[i][j];
    if (off < tol) break;
    for (int pi = 0; pi < 5; ++pi)
      for (int qi = pi + 1; qi < 6; ++qi) {
        double apq = A[pi][qi];
        if (fabs(apq) < 1e-300) continue;
        double app = A[pi][pi], aqq = A[qi][qi];
        double tau = (aqq - app) / (2.0 * apq);
        double tt = (tau >= 0.0) ? 1.0 / (tau + sqrt(1.0 + tau * tau))
                                 : 1.0 / (tau - sqrt(1.0 + tau * tau));
        double c = 1.0 / sqrt(1.0 + tt * tt), s = tt * c;
        for (int k = 0; k < 6; ++k) {
          double akp = A[k][pi], akq = A[k][qi];
          A[k][pi] = c * akp - s * akq; A[k][qi] = s * akp + c * akq;
        }
        for (int k = 0; k < 6; ++k) {
          double apk = A[pi][k], aqk = A[qi][k];
          A[pi][k] = c * apk - s * aqk; A[qi][k] = s * apk + c * aqk;
        }
        for (int k = 0; k < 6; ++k) {
          double vkp = V[k][pi], vkq = V[k][qi];
          V[k][pi] = c * vkp - s * vkq; V[k][qi] = s * vkp + c * vkq;
        }
      }
  }
  int idx[6] = {0, 1, 2, 3, 4, 5};
  for (int a = 0; a < 5; ++a)
    for (int b = 0; b < 5 - a; ++b)
      if (A[idx[b]][idx[b]] < A[idx[b + 1]][idx[b + 1]]) {
        int tmp = idx[b]; idx[b] = idx[b + 1]; idx[b + 1] = tmp;
      }
  for (int k = 0; k < 6; ++k) {
    double lam = A[idx[k]][idx[k]];
    rs[k] = (float)(1.0 / sqrt(fmax(lam, 1e-30)));
    for (int j = 0; j < 6; ++j) Wm[j * 6 + k] = (float)V[j][idx[k]];
  }
}

// V8[n,k] = (sum_j Bt[n,j]*Wm[j,k]) * rs[k];  cols 6,7 zeroed
__global__ void v_scale(const float* __restrict__ Bt, const float* __restrict__ Wm,
                        const float* __restrict__ rs, float* __restrict__ V8) {
  __shared__ float Ws[36], rss[6];
  if (threadIdx.x < 36) Ws[threadIdx.x] = Wm[threadIdx.x];
  if (threadIdx.x < 6) rss[threadIdx.x] = rs[threadIdx.x];
  __syncthreads();
  int n = blockIdx.x * 256 + threadIdx.x;
  float b[6];
#pragma unroll
  for (int j = 0; j < 6; ++j) b[j] = Bt[(size_t)n * 8 + j];
#pragma unroll
  for (int k = 0; k < 6; ++k) {
    float s = 0.f;
#pragma unroll
    for (int j = 0; j < 6; ++j) s += b[j] * Ws[j * 6 + k];
    V8[(size_t)n * 8 + k] = s * rss[k];
  }
  V8[(size_t)n * 8 + 6] = 0.f;
  V8[(size_t)n * 8 + 7] = 0.f;
}

__global__ void pad8(const float* __restrict__ src, float* __restrict__ dst) {
  int n = blockIdx.x * 256 + threadIdx.x;
#pragma unroll
  for (int k = 0; k < 6; ++k) dst[(size_t)n * 8 + k] = src[(size_t)n * 6 + k];
  dst[(size_t)n * 8 + 6] = 0.f;
  dst[(size_t)n * 8 + 7] = 0.f;
}

__global__ void pack3(const float* __restrict__ V8, float* __restrict__ W) {
  int n = blockIdx.x * 256 + threadIdx.x;
  W[(size_t)n * 4 + 0] = V8[(size_t)n * 8 + 0];
  W[(size_t)n * 4 + 1] = V8[(size_t)n * 8 + 1];
  W[(size_t)n * 4 + 2] = V8[(size_t)n * 8 + 2];
  W[(size_t)n * 4 + 3] = 0.f;
}

// out[n*FCpad+t] = base[n]*prod_{bit b of t} U[b*N+n], t<nterms; zero pad
__global__ void build_W(float* __restrict__ out, int FCpad, int nterms, int nu,
                        const float* __restrict__ base, int bstride, int boff,
                        const float* __restrict__ U, const float* __restrict__ SC,
                        int rs_idx) {
  int n = blockIdx.x * 256 + threadIdx.x;
  float bv = base[(size_t)n * bstride + boff];
  if (rs_idx >= 0) bv *= rsqrtf(SC[rs_idx]);
  float uv[3];
  for (int b = 0; b < 3; ++b) uv[b] = (b < nu) ? U[(size_t)b * N + n] : 0.f;
  for (int t = 0; t < FCpad; ++t) {
    float v = 0.f;
    if (t < nterms) {
      v = bv;
      for (int b = 0; b < nu; ++b)
        if ((t >> b) & 1) v *= uv[b];
    }
    out[(size_t)n * FCpad + t] = v;
  }
}

// y[n] = sum_t (-1)^popc(t) * (prod_{b in t} U_b[n]) * Y[n*FCpad+t]
__global__ void combine_y(float* __restrict__ y, const float* __restrict__ Y,
                          int FCpad, int nterms, int nu, const float* __restrict__ U) {
  int n = blockIdx.x * 256 + threadIdx.x;
  float uv[3];
  for (int b = 0; b < 3; ++b) uv[b] = (b < nu) ? U[(size_t)b * N + n] : 0.f;
  float s = 0.f;
  for (int t = 0; t < nterms; ++t) {
    float w = Y[(size_t)n * FCpad + t];
    int pc = 0;
    for (int b = 0; b < nu; ++b)
      if ((t >> b) & 1) { w *= uv[b]; ++pc; }
    s += (pc & 1) ? -w : w;
  }
  y[n] = s;
}

__global__ void cols_sumsq(const float* __restrict__ X, int stride, int ncols,
                           float* __restrict__ SC, int idx0) {
  const int t = threadIdx.x;
  const int lane = t & 63, wave = t >> 6;
  const int n = blockIdx.x * 256 + t;
  float a[8];
#pragma unroll
  for (int c = 0; c < 8; ++c) a[c] = 0.f;
  for (int c = 0; c < ncols; ++c) {
    float v = X[(size_t)n * stride + c];
    a[c] = v * v;
  }
  for (int c = 0; c < ncols; ++c)
    for (int off = 32; off; off >>= 1) a[c] += __shfl_down(a[c], off);
  __shared__ float part[4][8];
  if (lane == 0)
    for (int c = 0; c < ncols; ++c) part[wave][c] = a[c];
  __syncthreads();
  if (t == 0)
    for (int c = 0; c < ncols; ++c)
      atomicAdd(&SC[idx0 + c], part[0][c] + part[1][c] + part[2][c] + part[3][c]);
}

__global__ void vec_dot(const float* __restrict__ A, int sa, int oa,
                        const float* __restrict__ B, int sb, int ob,
                        float* __restrict__ SC, int idx) {
  const int t = threadIdx.x;
  const int lane = t & 63, wave = t >> 6;
  const int n = blockIdx.x * 256 + t;
  float v = A[(size_t)n * sa + oa] * B[(size_t)n * sb + ob];
  for (int off = 32; off; off >>= 1) v += __shfl_down(v, off);
  __shared__ float part[4];
  if (lane == 0) part[wave] = v;
  __syncthreads();
  if (t == 0) atomicAdd(&SC[idx], part[0] + part[1] + part[2] + part[3]);
}

__global__ void vscale1(float* __restrict__ out, const float* __restrict__ in,
                        int stride, int off, const float* __restrict__ SC, int rs_idx) {
  int n = blockIdx.x * 256 + threadIdx.x;
  float v = in[(size_t)n * stride + off];
  if (rs_idx >= 0) v *= rsqrtf(SC[rs_idx]);
  out[n] = v;
}

__global__ void axpy3(float* __restrict__ out, const float* __restrict__ Y, int stride,
                      int off, const float* __restrict__ q0, const float* __restrict__ q1,
                      const float* __restrict__ q2, const float* __restrict__ SC,
                      int c0, int c1, int c2, int np, int coef_rs, int out_rs) {
  int n = blockIdx.x * 256 + threadIdx.x;
  float crs = (coef_rs >= 0) ? rsqrtf(SC[coef_rs]) : 1.f;
  float s = Y[(size_t)n * stride + off];
  if (np > 0) s -= SC[c0] * crs * q0[n];
  if (np > 1) s -= SC[c1] * crs * q1[n];
  if (np > 2) s -= SC[c2] * crs * q2[n];
  if (out_rs >= 0) s *= rsqrtf(SC[out_rs]);
  out[n] = s;
}

__global__ void nuc_accum(float* __restrict__ SC, int mode, int z0, int nterms,
                          int ny0, int dps, int nd) {
  if (threadIdx.x || blockIdx.x) return;
  float add = 0.f;
  if (mode == 0) {
    for (int k = 0; k < 3; ++k) add += sqrtf(fabsf(SC[z0 + k] / SC[ny0 + k]));
  } else if (mode == 1) {
    float vmv = 0.f;
    for (int t = 0; t < nterms; ++t) {
      int pc = __popc(t);
      vmv += (pc & 1) ? -SC[z0 + t] : SC[z0 + t];
    }
    add = sqrtf(fabsf(vmv / SC[ny0]));
  } else {
    float vmv = SC[z0];
    for (int t = 0; t < nd; ++t) vmv -= SC[dps + 2 * t] * SC[dps + 2 * t + 1];
    add = sqrtf(fabsf(vmv / SC[ny0]));
  }
  SC[5] += add;
}

__global__ void finalize_k(const float* __restrict__ SC, float* __restrict__ out) {
  if (threadIdx.x || blockIdx.x) return;
  const float Ef = (float)EDG;
  float m1 = SC[0] / Ef, v1 = SC[1] / Ef - m1 * m1;
  float m2 = SC[2] / Ef, v2 = SC[3] / Ef - m2 * m2;
  out[131072] = 0.01f * (v1 + v2) + 0.01f * SC[5];
  out[393217] = SC[4] / (float)N;
}

// ---------------------------------------------------------------------------
extern "C" void kernel_launch(void* const* d_in, const int* in_sizes, int n_in,
                              void* d_out, int out_size, void* d_ws, size_t ws_size,
                              hipStream_t stream) {
  const float* x      = (const float*)d_in[0];
  const int*   ei     = (const int*)  d_in[1];
  const float* gcn1_w = (const float*)d_in[2];
  const float* gcn1_b = (const float*)d_in[3];
  const float* gcn2_w = (const float*)d_in[4];
  const float* gcn2_b = (const float*)d_in[5];
  const float* p1w1   = (const float*)d_in[6];
  const float* p1b1   = (const float*)d_in[7];
  const float* p1w2   = (const float*)d_in[8];
  const float* p1b2   = (const float*)d_in[9];
  const float* p2w1   = (const float*)d_in[10];
  const float* p2b1   = (const float*)d_in[11];
  const float* p2w2   = (const float*)d_in[12];
  const float* p2b2   = (const float*)d_in[13];
  const float* omega1 = (const float*)d_in[14];
  const float* omega2 = (const float*)d_in[15];
  float* out = (float*)d_out;

  float* ws = (float*)d_ws;
  size_t o = 0;
  auto alloc = [&](size_t nf) { float* p = ws + o; o += nf; return p; };
  // dense node buffers
  float* xw1  = alloc((size_t)N * 64);
  float* xh   = alloc((size_t)N * 64);
  float* x1   = alloc((size_t)N * 64);
  float* P    = alloc((size_t)N * 64);
  float* x1w  = alloc((size_t)N * 32);
  float* xh2  = alloc((size_t)N * 16);
  float* dis1 = alloc(N);
  float* dis2 = alloc(N);
  float* Qb8  = alloc((size_t)N * 8);
  float* Zi8  = alloc((size_t)N * 8);
  float* Bt8  = alloc((size_t)N * 8);
  float* V8   = alloc((size_t)N * 8);
  float* W8   = alloc((size_t)N * 8);
  float* T8   = alloc((size_t)N * 8);
  float* Y8   = alloc((size_t)N * 8);
  float* Zz8  = alloc((size_t)N * 8);
  float* P8   = alloc((size_t)N * 8);
  float* yv   = alloc(N);
  float* Uv   = alloc((size_t)3 * N);
  float* Pv   = alloc((size_t)3 * N);
  float* SMF  = alloc(64);            // Wm[36] + rs[6]
  // zeroed block: cnt(2N int) | deg1 | deg2 | SC
  float* zb   = alloc((size_t)4 * N + 256);
  int*   cnt  = (int*)zb;
  float* deg1 = zb + 2 * N;
  float* deg2 = deg1 + N;
  float* SC   = deg2 + N;
  const size_t zero_bytes = ((size_t)4 * N + 256) * sizeof(float);
  // CSR structures (ints)
  int* rowptr = (int*)alloc(2 * (N + 1) + 2);   // src then dst
  int* cur    = (int*)alloc(2 * N);
  int* col_s  = (int*)alloc(EDG);
  int* perm_s = (int*)alloc(EDG);
  int* col_d  = (int*)alloc(EDG);
  int* perm_d = (int*)alloc(EDG);
  float* w1s  = alloc(EDG);
  float* w1d  = alloc(EDG);
  float* w2s  = alloc(EDG);
  float* w2d  = alloc(EDG);
  o = (o + 1) & ~(size_t)1;
  double* Gd = (double*)(ws + o); o += 48;   // 21 doubles (padded)
  double* Rd = (double*)(ws + o); o += 80;   // 36 doubles (padded)
  if (ws_size < o * sizeof(float)) return;   // insufficient scratch -> loud failure

  const int* rp_s = rowptr;
  const int* rp_d = rowptr + (N + 1);

  // SC slots
  enum {
    A_NY = 8,  A_Z = 11,
    A_NY3 = 14, A_Z3 = 15,
    A_NY4 = 17, A_Z4 = 18,
    A_NY5 = 22, A_Z5 = 23,
    B_NY = 34, B_Z = 37,
    B_C3 = 40, B_NY3 = 41, B_ZZ3 = 42, B_DP3 = 43,
    B_C4 = 45, B_NY4 = 47, B_ZZ4 = 48, B_DP4 = 49,
    B_C5 = 53, B_NY5 = 56, B_ZZ5 = 57, B_DP5 = 58
  };

  // SpMM wrappers: A = by-src CSR; AT = by-dst CSR. eps via colsum when EPSC.
  auto spA8 = [&](const float* w, const float* X, float* O) {
    spmm<8, 1><<<128, 256, 0, stream>>>(rp_s, col_s, w, X, O, GEPS); };
  auto spAT8 = [&](const float* w, const float* X, float* O) {
    spmm<8, 1><<<128, 256, 0, stream>>>(rp_d, col_d, w, X, O, GEPS); };
  auto spA4 = [&](const float* w, const float* X, float* O) {
    spmm<4, 1><<<64, 256, 0, stream>>>(rp_s, col_s, w, X, O, GEPS); };
  auto spAT4 = [&](const float* w, const float* X, float* O) {
    spmm<4, 1><<<64, 256, 0, stream>>>(rp_d, col_d, w, X, O, GEPS); };

  auto run_svd = [&](const float* wsrc, const float* wdst, const float* omega) {
    pad8<<<16, 256, 0, stream>>>(omega, W8);
    spA8(wsrc, W8, Qb8);
    gram6<<<1, 256, 0, stream>>>(Qb8, 8, Gd, Rd, 1);
    cholqr_apply<<<16, 256, 0, stream>>>(Qb8, 8, Rd);
    for (int itp = 0; itp < 2; ++itp) {
      spAT8(wdst, Qb8, Zi8);
      gram6<<<1, 256, 0, stream>>>(Zi8, 8, Gd, Rd, 1);
      cholqr_apply<<<16, 256, 0, stream>>>(Zi8, 8, Rd);
      spA8(wsrc, Zi8, Qb8);
      gram6<<<1, 256, 0, stream>>>(Qb8, 8, Gd, Rd, 1);
      cholqr_apply<<<16, 256, 0, stream>>>(Qb8, 8, Rd);
    }
    spAT8(wdst, Qb8, Bt8);
    gram6<<<1, 256, 0, stream>>>(Bt8, 8, Gd, nullptr, 0);
    jacobi6<<<1, 1, 0, stream>>>(Gd, SMF, SMF + 36);
    v_scale<<<16, 256, 0, stream>>>(Bt8, SMF, SMF + 36, V8);
  };

  auto nuc_batch3 = [&](const float* wsrc, const float* wdst, int nyIdx, int zIdx) {
    pack3<<<16, 256, 0, stream>>>(V8, W8);
    spAT4(wdst, W8, T8);
    spA4(wsrc, T8, Y8);
    cols_sumsq<<<16, 256, 0, stream>>>(Y8, 4, 3, SC, nyIdx);
    spAT4(wdst, Y8, Zz8);
    cols_sumsq<<<16, 256, 0, stream>>>(Zz8, 4, 3, SC, zIdx);
    nuc_accum<<<1, 1, 0, stream>>>(SC, 0, zIdx, 3, nyIdx, 0, 0);
    vscale1<<<16, 256, 0, stream>>>(Uv, Y8, 4, 2, SC, nyIdx + 2);  // u2
  };

  // ===================== init + CSR build (structure shared by both layers) ==
  hipMemsetAsync(zb, 0, zero_bytes, stream);
  hist_edges<<<512, 256, 0, stream>>>(ei, cnt);
  scan2x<<<2, 256, 0, stream>>>(cnt, rowptr, cur);
  scatter_edges<<<512, 256, 0, stream>>>(ei, cur, col_s, perm_s, col_d, perm_d);

  // ===================== graph 1: gate + conv =====================
  mm_small<64><<<64, 256, 0, stream>>>(x, p1w1, xw1, 512, nullptr);
  edge_gate1<<<2048, 256, 0, stream>>>(xw1, ei, p1b1, p1w2, p1b2,
                                       out + 131073, deg1, SC + 0);
  gather_w2<<<512, 256, 0, stream>>>(out + 131073, perm_s, perm_d, w1s, w1d);
  make_dis<<<16, 256, 0, stream>>>(deg1, dis1);
  mm_small<64><<<64, 256, 0, stream>>>(x, gcn1_w, xh, 512, dis1);  // xh = dis*h
  spmm<64, 0><<<1024, 256, 0, stream>>>(rp_d, col_d, w1d, xh, P, 0.f);
  conv_epi64<<<1024, 256, 0, stream>>>(P, xh, dis1, gcn1_b, x1);

  // ===================== SVD1 + nuc1 (elementwise deflation) =====================
  run_svd(w1s, w1d, omega1);
  nuc_batch3(w1s, w1d, A_NY, A_Z);
  {
    const int NYk[3] = {A_NY3, A_NY4, A_NY5};
    const int Zk[3]  = {A_Z3, A_Z4, A_Z5};
    for (int k = 3; k <= 5; ++k) {
      int nu = k - 2, nt = 1 << nu;
      int ny = NYk[k - 3], zz = Zk[k - 3];
      if (k < 5) {
        build_W<<<16, 256, 0, stream>>>(W8, 4, nt, nu, V8, 8, k, Uv, SC, -1);
        spAT4(w1d, W8, T8);
        spA4(w1s, T8, Y8);
        combine_y<<<16, 256, 0, stream>>>(yv, Y8, 4, nt, nu, Uv);
        cols_sumsq<<<16, 256, 0, stream>>>(yv, 1, 1, SC, ny);
        build_W<<<16, 256, 0, stream>>>(W8, 4, nt, nu, yv, 1, 0, Uv, SC, -1);
        spAT4(w1d, W8, Zz8);
        cols_sumsq<<<16, 256, 0, stream>>>(Zz8, 4, nt, SC, zz);
      } else {
        build_W<<<16, 256, 0, stream>>>(W8, 8, nt, nu, V8, 8, k, Uv, SC, -1);
        spAT8(w1d, W8, T8);
        spA8(w1s, T8, Y8);
        combine_y<<<16, 256, 0, stream>>>(yv, Y8, 8, nt, nu, Uv);
        cols_sumsq<<<16, 256, 0, stream>>>(yv, 1, 1, SC, ny);
        build_W<<<16, 256, 0, stream>>>(W8, 8, nt, nu, yv, 1, 0, Uv, SC, -1);
        spAT8(w1d, W8, Zz8);
        cols_sumsq<<<16, 256, 0, stream>>>(Zz8, 8, nt, SC, zz);
      }
      nuc_accum<<<1, 1, 0, stream>>>(SC, 1, zz, nt, ny, 0, 0);
      if (k < 5)
        vscale1<<<16, 256, 0, stream>>>(Uv + (size_t)(k - 2) * N, yv, 1, 0, SC, ny);
    }
  }

  // ===================== graph 2: gate + conv + outputs =====================
  mm_small<32><<<64, 256, 0, stream>>>(x1, p2w1, x1w, 64, nullptr);
  edge_gate2<<<1024, 256, 0, stream>>>(x1w, ei, p2b1, p2w2, p2b2,
                                       out + 262145, deg2, SC + 2);
  gather_w2<<<512, 256, 0, stream>>>(out + 262145, perm_s, perm_d, w2s, w2d);
  make_dis<<<16, 256, 0, stream>>>(deg2, dis2);
  mm_small<16><<<64, 256, 0, stream>>>(x1, gcn2_w, xh2, 64, dis2);  // xh2 = dis*h
  spmm<16, 0><<<256, 256, 0, stream>>>(rp_d, col_d, w2d, xh2, P, 0.f);
  conv2_softmax<<<16, 256, 0, stream>>>(P, xh2, dis2, gcn2_b, out, out + 65536, SC);

  // ===================== SVD2 + nuc2 (rank-1 deflation) =====================
  run_svd(w2s, w2d, omega2);
  nuc_batch3(w2s, w2d, B_NY, B_Z);
  // p2 = A @ (Z col2 * rsqrt(ny2))
  build_W<<<16, 256, 0, stream>>>(W8, 4, 1, 0, Zz8, 4, 2, nullptr, SC, B_NY + 2);
  spA4(w2s, W8, P8);
  vscale1<<<16, 256, 0, stream>>>(Pv, P8, 4, 0, SC, -1);
  {
    const int Ck[3]  = {B_C3, B_C4, B_C5};
    const int NYk[3] = {B_NY3, B_NY4, B_NY5};
    const int ZZk[3] = {B_ZZ3, B_ZZ4, B_ZZ5};
    const int DPk[3] = {B_DP3, B_DP4, B_DP5};
    for (int k = 3; k <= 5; ++k) {
      int nd = k - 2;
      int C = Ck[k - 3], ny = NYk[k - 3], zz = ZZk[k - 3], dp = DPk[k - 3];
      for (int t = 0; t < nd; ++t)
        vec_dot<<<16, 256, 0, stream>>>(Uv + (size_t)t * N, 1, 0, V8, 8, k, SC, C + t);
      build_W<<<16, 256, 0, stream>>>(W8, 4, 1, 0, V8, 8, k, nullptr, SC, -1);
      spAT4(w2d, W8, T8);
      spA4(w2s, T8, Y8);
      axpy3<<<16, 256, 0, stream>>>(yv, Y8, 4, 0, Pv, Pv + N, Pv + 2 * N,
                                    SC, C, C + 1, C + 2, nd, -1, -1);
      cols_sumsq<<<16, 256, 0, stream>>>(yv, 1, 1, SC, ny);
      build_W<<<16, 256, 0, stream>>>(W8, 4, 1, 0, yv, 1, 0, nullptr, SC, -1);
      spAT4(w2d, W8, Zz8);
      cols_sumsq<<<16, 256, 0, stream>>>(Zz8, 4, 1, SC, zz);
      for (int t = 0; t < nd; ++t) {
        vec_dot<<<16, 256, 0, stream>>>(yv, 1, 0, Pv + (size_t)t * N, 1, 0, SC, dp + 2 * t);
        vec_dot<<<16, 256, 0, stream>>>(Uv + (size_t)t * N, 1, 0, yv, 1, 0, SC, dp + 2 * t + 1);
      }
      nuc_accum<<<1, 1, 0, stream>>>(SC, 2, zz, 0, ny, dp, nd);
      if (k < 5) {
        vscale1<<<16, 256, 0, stream>>>(Uv + (size_t)(k - 2) * N, yv, 1, 0, SC, ny);
        build_W<<<16, 256, 0, stream>>>(W8, 4, 1, 0, Zz8, 4, 0, nullptr, SC, ny);
        spA4(w2s, W8, P8);
        axpy3<<<16, 256, 0, stream>>>(Pv + (size_t)(k - 2) * N, P8, 4, 0,
                                      Pv, Pv + N, Pv + 2 * N,
                                      SC, dp + 1, dp + 3, dp + 5, nd, ny, -1);
      }
    }
  }

  finalize_k<<<1, 1, 0, stream>>>(SC, out);
}

// Round 4
// 1205.144 us; speedup vs baseline: 3.3449x; 1.9622x over previous
//
#include <hip/hip_runtime.h>
#include <cmath>

constexpr int N = 4096;
constexpr int EDG = 131072;
constexpr float GEPS = 1e-6f;

// ---------------------------------------------------------------------------
// block-wide reduction helper: sums vals[0..cnt-1] over 256 threads.
// Returns pointer to shared tot[8] (valid for all threads after return).
__device__ __forceinline__ float* blk_sums(float* vals, int cnt) {
  __shared__ float part[4][8];
  __shared__ float tot[8];
  const int lane = threadIdx.x & 63, wv = threadIdx.x >> 6;
  for (int c = 0; c < cnt; ++c) {
    float v = vals[c];
    for (int off = 32; off; off >>= 1) v += __shfl_down(v, off);
    if (lane == 0) part[wv][c] = v;
  }
  __syncthreads();
  if (threadIdx.x == 0)
    for (int c = 0; c < cnt; ++c)
      tot[c] = part[0][c] + part[1][c] + part[2][c] + part[3][c];
  __syncthreads();
  return tot;
}

// ---------------------------------------------------------------------------
// CSR build
__global__ void hist_edges(const int* __restrict__ ei, int* __restrict__ cnt) {
  int e = blockIdx.x * 256 + threadIdx.x;
  atomicAdd(&cnt[ei[e]], 1);
  atomicAdd(&cnt[N + ei[EDG + e]], 1);
}

__global__ __launch_bounds__(256) void scan2x(const int* __restrict__ cnt,
                                              int* __restrict__ rowptr,
                                              int* __restrict__ cur) {
  const int b = blockIdx.x;
  const int* c = cnt + b * N;
  int* rp = rowptr + b * (N + 1);
  int* cu = cur + b * N;
  __shared__ int part[256];
  const int t = threadIdx.x;
  int local[16], s = 0;
  const int base = t * 16;
  for (int i = 0; i < 16; ++i) { local[i] = s; s += c[base + i]; }
  part[t] = s;
  __syncthreads();
  if (t == 0) {
    int acc = 0;
    for (int i = 0; i < 256; ++i) { int v = part[i]; part[i] = acc; acc += v; }
  }
  __syncthreads();
  const int off = part[t];
  for (int i = 0; i < 16; ++i) { rp[base + i] = off + local[i]; cu[base + i] = off + local[i]; }
  if (t == 255) rp[N] = off + s;
}

__global__ void scatter_edges(const int* __restrict__ ei, int* __restrict__ cur,
                              int* __restrict__ col_s, int* __restrict__ perm_s,
                              int* __restrict__ col_d, int* __restrict__ perm_d) {
  int e = blockIdx.x * 256 + threadIdx.x;
  int s = ei[e], d = ei[EDG + e];
  int ps = atomicAdd(&cur[s], 1);
  col_s[ps] = d; perm_s[ps] = e;
  int pd = atomicAdd(&cur[N + d], 1);
  col_d[pd] = s; perm_d[pd] = e;
}

__global__ void gather_w2(const float* __restrict__ s, const int* __restrict__ perm_s,
                          const int* __restrict__ perm_d, float* __restrict__ ws_,
                          float* __restrict__ wd_) {
  int p = blockIdx.x * 256 + threadIdx.x;
  ws_[p] = s[perm_s[p]];
  wd_[p] = s[perm_d[p]];
}

// ---------------------------------------------------------------------------
// SpMM: OUT[r,f] = sum_{e in row r} w[e]*(dis?dis[c]:1)*X[c,f] + eps*CS[cs+f]
// wave per row; lane = es*F + f. Optional per-column output sum/sumsq atomics.
template<int F, int DIS>
__global__ __launch_bounds__(256) void spmm(const int* __restrict__ rowptr,
                                            const int* __restrict__ col,
                                            const float* __restrict__ w,
                                            const float* __restrict__ X,
                                            const float* __restrict__ dis,
                                            float* __restrict__ OUT,
                                            float* __restrict__ SC, int cs_idx,
                                            float eps, int osum, int ossq) {
  constexpr int ES = 64 / F;
  const int lane = threadIdx.x & 63;
  const int wv = threadIdx.x >> 6;
  const int f = lane & (F - 1);
  const int es = lane / F;
  const int r = blockIdx.x * 4 + wv;
  const int e0 = rowptr[r], e1 = rowptr[r + 1];
  float acc = 0.f;
  for (int e = e0 + es; e < e1; e += ES) {
    int c = col[e];
    float wx = w[e];
    if (DIS) wx *= dis[c];
    acc += wx * X[(size_t)c * F + f];
  }
#pragma unroll
  for (int off = F; off < 64; off <<= 1) acc += __shfl_xor(acc, off);
  float o = acc + ((cs_idx >= 0) ? eps * SC[cs_idx + f] : 0.f);
  if (es == 0) OUT[(size_t)r * F + f] = o;
  if (osum >= 0 || ossq >= 0) {
    __shared__ float bs[8], bq[8];
    if (threadIdx.x < F) { bs[threadIdx.x] = 0.f; bq[threadIdx.x] = 0.f; }
    __syncthreads();
    if (es == 0) {
      if (osum >= 0) atomicAdd(&bs[f], o);
      if (ossq >= 0) atomicAdd(&bq[f], o * o);
    }
    __syncthreads();
    if (threadIdx.x < F) {
      if (osum >= 0) atomicAdd(&SC[osum + threadIdx.x], bs[threadIdx.x]);
      if (ossq >= 0) atomicAdd(&SC[ossq + threadIdx.x], bq[threadIdx.x]);
    }
  }
}

// ---------------------------------------------------------------------------
// Fused layer-1 GEMM: O1 = A@W1, O2 = A@W2.  A[4096,512], W*[512,64].
__global__ __launch_bounds__(256) void gemm512(const float* __restrict__ A,
                                               const float* __restrict__ W1,
                                               const float* __restrict__ W2,
                                               float* __restrict__ O1,
                                               float* __restrict__ O2) {
  __shared__ float As[16][33];
  __shared__ float Ws[32][128];
  const int t = threadIdx.x;
  const int r = t >> 4;
  const int cg = t & 15;
  const int r0 = blockIdx.x * 16;
  float acc[8];
#pragma unroll
  for (int j = 0; j < 8; ++j) acc[j] = 0.f;
  for (int k0 = 0; k0 < 512; k0 += 32) {
    __syncthreads();
    {
      int idx = t;
#pragma unroll
      for (int i = 0; i < 2; ++i, idx += 256) {
        int rr = idx >> 5, kk = idx & 31;
        As[rr][kk] = A[(size_t)(r0 + rr) * 512 + k0 + kk];
      }
    }
    for (int idx = t; idx < 32 * 128; idx += 256) {
      int kk = idx >> 7, c = idx & 127;
      Ws[kk][c] = (c < 64) ? W1[(size_t)(k0 + kk) * 64 + c]
                           : W2[(size_t)(k0 + kk) * 64 + c - 64];
    }
    __syncthreads();
#pragma unroll 4
    for (int kk = 0; kk < 32; ++kk) {
      float a = As[r][kk];
      const float* wr = &Ws[kk][cg * 8];
#pragma unroll
      for (int j = 0; j < 8; ++j) acc[j] += a * wr[j];
    }
  }
  int n = r0 + r;
  if (cg < 8) {
#pragma unroll
    for (int j = 0; j < 8; ++j) O1[(size_t)n * 64 + cg * 8 + j] = acc[j];
  } else {
#pragma unroll
    for (int j = 0; j < 8; ++j) O2[(size_t)n * 64 + (cg - 8) * 8 + j] = acc[j];
  }
}

// Fused layer-2 GEMM: O1[4096,32]=A@W1, O2[4096,16]=A@W2. A[4096,64].
__global__ __launch_bounds__(256) void gemm64(const float* __restrict__ A,
                                              const float* __restrict__ W1,
                                              const float* __restrict__ W2,
                                              float* __restrict__ O1,
                                              float* __restrict__ O2) {
  __shared__ float As[32][65];
  __shared__ float Ws[64][48];
  const int t = threadIdx.x;
  const int r = t >> 3;
  const int cg = t & 7;
  const int r0 = blockIdx.x * 32;
  for (int idx = t; idx < 32 * 64; idx += 256)
    As[idx >> 6][idx & 63] = A[(size_t)(r0 + (idx >> 6)) * 64 + (idx & 63)];
  for (int idx = t; idx < 64 * 48; idx += 256) {
    int kk = idx / 48, c = idx % 48;
    Ws[kk][c] = (c < 32) ? W1[kk * 32 + c] : W2[kk * 16 + c - 32];
  }
  __syncthreads();
  float acc[6] = {0.f, 0.f, 0.f, 0.f, 0.f, 0.f};
  for (int k = 0; k < 64; ++k) {
    float a = As[r][k];
#pragma unroll
    for (int j = 0; j < 6; ++j) acc[j] += a * Ws[k][cg + 8 * j];
  }
  int n = r0 + r;
#pragma unroll
  for (int j = 0; j < 6; ++j) {
    int c = cg + 8 * j;
    if (c < 32) O1[(size_t)n * 32 + c] = acc[j];
    else O2[(size_t)n * 16 + c - 32] = acc[j];
  }
}

// ---------------------------------------------------------------------------
__global__ void edge_gate1(const float* __restrict__ xw, const int* __restrict__ ei,
                           const float* __restrict__ b1, const float* __restrict__ w2,
                           const float* __restrict__ b2, float* __restrict__ s_out,
                           float* __restrict__ deg, float* __restrict__ SCs) {
  const int lane = threadIdx.x & 63;
  const int wave = threadIdx.x >> 6;
  const float b1v = b1[lane];
  const float w2v = w2[lane];
  const float b2s = b2[0];
  float lsum = 0.f, lssq = 0.f;
  for (int it = 0; it < 16; ++it) {
    const int e = blockIdx.x * 64 + it * 4 + wave;
    const int s = ei[e];
    const int d = ei[EDG + e];
    float g = xw[(size_t)s * 64 + lane] - xw[(size_t)d * 64 + lane] + b1v;
    g = fmaxf(g, 0.f) * w2v;
#pragma unroll
    for (int off = 32; off; off >>= 1) g += __shfl_down(g, off);
    if (lane == 0) {
      float agg = g + b2s;
      agg *= agg;
      float sv = 1.f / (1.f + __expf(-agg));
      s_out[e] = sv;
      atomicAdd(&deg[d], sv);
      lsum += sv; lssq += sv * sv;
    }
  }
  __shared__ float red[8];
  if (lane == 0) { red[wave] = lsum; red[4 + wave] = lssq; }
  __syncthreads();
  if (threadIdx.x == 0) {
    atomicAdd(&SCs[0], red[0] + red[1] + red[2] + red[3]);
    atomicAdd(&SCs[1], red[4] + red[5] + red[6] + red[7]);
  }
}

__global__ void edge_gate2(const float* __restrict__ xw, const int* __restrict__ ei,
                           const float* __restrict__ b1, const float* __restrict__ w2,
                           const float* __restrict__ b2, float* __restrict__ s_out,
                           float* __restrict__ deg, float* __restrict__ SCs) {
  const int half = threadIdx.x & 31;
  const int wi = threadIdx.x >> 5;
  const float b1v = b1[half];
  const float w2v = w2[half];
  const float b2s = b2[0];
  float lsum = 0.f, lssq = 0.f;
  for (int it = 0; it < 16; ++it) {
    const int e = blockIdx.x * 128 + it * 8 + wi;
    const int s = ei[e];
    const int d = ei[EDG + e];
    float g = xw[(size_t)s * 32 + half] - xw[(size_t)d * 32 + half] + b1v;
    g = fmaxf(g, 0.f) * w2v;
#pragma unroll
    for (int off = 16; off; off >>= 1) g += __shfl_down(g, off, 32);
    if (half == 0) {
      float agg = g + b2s;
      agg *= agg;
      float sv = 1.f / (1.f + __expf(-agg));
      s_out[e] = sv;
      atomicAdd(&deg[d], sv);
      lsum += sv; lssq += sv * sv;
    }
  }
  __shared__ float red[16];
  if (half == 0) { red[wi] = lsum; red[8 + wi] = lssq; }
  __syncthreads();
  if (threadIdx.x == 0) {
    float a = 0.f, b = 0.f;
    for (int i = 0; i < 8; ++i) { a += red[i]; b += red[8 + i]; }
    atomicAdd(&SCs[0], a);
    atomicAdd(&SCs[1], b);
  }
}

// ---------------------------------------------------------------------------
__global__ void make_dis(const float* __restrict__ deg, float* __restrict__ dis) {
  int n = blockIdx.x * 256 + threadIdx.x;
  dis[n] = rsqrtf(deg[n] + 1.0f);
}

// x1 = relu(dis*P + dis^2*h + bias)
__global__ void conv_epi64(const float* __restrict__ P, const float* __restrict__ h,
                           const float* __restrict__ dis, const float* __restrict__ bias,
                           float* __restrict__ out) {
  int i = blockIdx.x * 256 + threadIdx.x;
  int n = i >> 6, f = i & 63;
  float d = dis[n];
  float v = d * (P[i] + d * h[i]) + bias[f];
  out[i] = fmaxf(v, 0.f);
}

__global__ void conv2_softmax(const float* __restrict__ P, const float* __restrict__ h,
                              const float* __restrict__ dis, const float* __restrict__ bias,
                              float* __restrict__ ls, float* __restrict__ sm,
                              float* __restrict__ SC) {
  const int t = threadIdx.x;
  const int r = blockIdx.x * 256 + t;
  const float d = dis[r];
  float v[16];
  float mx = -3.0e38f, mx2 = -3.0e38f;
#pragma unroll
  for (int c = 0; c < 16; ++c) {
    v[c] = d * (P[(size_t)r * 16 + c] + d * h[(size_t)r * 16 + c]) + bias[c];
    if (v[c] > mx) { mx2 = mx; mx = v[c]; }
    else if (v[c] > mx2) mx2 = v[c];
  }
  float se = 0.f;
#pragma unroll
  for (int c = 0; c < 16; ++c) se += expf(v[c] - mx);
  const float lse = mx + logf(se);
#pragma unroll
  for (int c = 0; c < 16; ++c) {
    float z = v[c] - lse;
    ls[(size_t)r * 16 + c] = z;
    sm[(size_t)r * 16 + c] = expf(z);
  }
  float calib = mx2 - mx;
  float* tot = blk_sums(&calib, 1);
  if (t == 0) atomicAdd(&SC[4], tot[0]);
}

// ---------------------------------------------------------------------------
// Gram of cols 0-5 (stride 8) -> 21 packed doubles via atomics (pre-zeroed).
__global__ void gram16(const float* __restrict__ Y, double* __restrict__ G) {
  const int t = threadIdx.x;
  const int lane = t & 63, wv = t >> 6;
  const int n = blockIdx.x * 256 + t;
  float y[6];
#pragma unroll
  for (int j = 0; j < 6; ++j) y[j] = Y[(size_t)n * 8 + j];
  float g[21];
  {
    int p = 0;
#pragma unroll
    for (int i = 0; i < 6; ++i)
#pragma unroll
      for (int j = i; j < 6; ++j) g[p++] = y[i] * y[j];
  }
#pragma unroll
  for (int p = 0; p < 21; ++p)
    for (int off = 32; off; off >>= 1) g[p] += __shfl_down(g[p], off);
  __shared__ float part[4][21];
  if (lane == 0)
    for (int p = 0; p < 21; ++p) part[wv][p] = g[p];
  __syncthreads();
  if (t < 21)
    atomicAdd(&G[t], (double)(part[0][t] + part[1][t] + part[2][t] + part[3][t]));
}

// Cholesky of packed-gram slot (redundant per block) + apply R^{-1} + colsum.
__global__ void chol_apply(float* __restrict__ Y, const double* __restrict__ G,
                           float* __restrict__ SC, int cs_idx) {
  __shared__ float Rs[36];
  if (threadIdx.x == 0) {
    double Gf[6][6];
    int p = 0;
    for (int i = 0; i < 6; ++i)
      for (int j = i; j < 6; ++j) { Gf[i][j] = G[p]; Gf[j][i] = G[p]; ++p; }
    double Rm[6][6];
    for (int i = 0; i < 6; ++i) for (int j = 0; j < 6; ++j) Rm[i][j] = 0.0;
    for (int j = 0; j < 6; ++j) {
      double s = Gf[j][j];
      for (int k = 0; k < j; ++k) s -= Rm[k][j] * Rm[k][j];
      double dj = sqrt(fmax(s, 1e-30));
      Rm[j][j] = dj;
      for (int i = j + 1; i < 6; ++i) {
        double v = Gf[j][i];
        for (int k = 0; k < j; ++k) v -= Rm[k][j] * Rm[k][i];
        Rm[j][i] = v / dj;
      }
    }
    for (int i = 0; i < 6; ++i)
      for (int j = 0; j < 6; ++j) Rs[i * 6 + j] = (float)Rm[i][j];
  }
  __syncthreads();
  int n = blockIdx.x * 256 + threadIdx.x;
  float y[6], q[6];
#pragma unroll
  for (int j = 0; j < 6; ++j) y[j] = Y[(size_t)n * 8 + j];
#pragma unroll
  for (int j = 0; j < 6; ++j) {
    float s = y[j];
#pragma unroll
    for (int i = 0; i < 6; ++i)
      if (i < j) s -= q[i] * Rs[i * 6 + j];
    q[j] = s / Rs[j * 6 + j];
  }
#pragma unroll
  for (int j = 0; j < 6; ++j) Y[(size_t)n * 8 + j] = q[j];
  float* tot = blk_sums(q, 6);
  if (threadIdx.x == 0)
    for (int j = 0; j < 6; ++j) atomicAdd(&SC[cs_idx + j], tot[j]);
}

__global__ void jacobi6(const double* __restrict__ G, float* __restrict__ Wm,
                        float* __restrict__ rs) {
  if (threadIdx.x || blockIdx.x) return;
  double A[6][6], V[6][6];
  int p = 0;
  for (int i = 0; i < 6; ++i)
    for (int j = i; j < 6; ++j) { A[i][j] = G[p]; A[j][i] = G[p]; ++p; }
  double tr = 0.0;
  for (int i = 0; i < 6; ++i) tr += fabs(A[i][i]);
  const double tol = 1e-26 * tr * tr + 1e-300;
  for (int i = 0; i < 6; ++i)
    for (int j = 0; j < 6; ++j) V[i][j] = (i == j) ? 1.0 : 0.0;
  for (int sweep = 0; sweep < 12; ++sweep) {
    double off = 0.0;
    for (int i = 0; i < 6; ++i)
      for (int j = i + 1; j < 6; ++j) off += A[i][j] * A[i][j];
    if (off < tol) break;
    for (int pi = 0; pi < 5; ++pi)
      for (int qi = pi + 1; qi < 6; ++qi) {
        double apq = A[pi][qi];
        if (fabs(apq) < 1e-300) continue;
        double app = A[pi][pi], aqq = A[qi][qi];
        double tau = (aqq - app) / (2.0 * apq);
        double tt = (tau >= 0.0) ? 1.0 / (tau + sqrt(1.0 + tau * tau))
                                 : 1.0 / (tau - sqrt(1.0 + tau * tau));
        double c = 1.0 / sqrt(1.0 + tt * tt), s = tt * c;
        for (int k = 0; k < 6; ++k) {
          double akp = A[k][pi], akq = A[k][qi];
          A[k][pi] = c * akp - s * akq; A[k][qi] = s * akp + c * akq;
        }
        for (int k = 0; k < 6; ++k) {
          double apk = A[pi][k], aqk = A[qi][k];
          A[pi][k] = c * apk - s * aqk; A[qi][k] = s * apk + c * aqk;
        }
        for (int k = 0; k < 6; ++k) {
          double vkp = V[k][pi], vkq = V[k][qi];
          V[k][pi] = c * vkp - s * vkq; V[k][qi] = s * vkp + c * vkq;
        }
      }
  }
  int idx[6] = {0, 1, 2, 3, 4, 5};
  for (int a = 0; a < 5; ++a)
    for (int b = 0; b < 5 - a; ++b)
      if (A[idx[b]][idx[b]] < A[idx[b + 1]][idx[b + 1]]) {
        int tmp = idx[b]; idx[b] = idx[b + 1]; idx[b + 1] = tmp;
      }
  for (int k = 0; k < 6; ++k) {
    double lam = A[idx[k]][idx[k]];
    rs[k] = (float)(1.0 / sqrt(fmax(lam, 1e-30)));
    for (int j = 0; j < 6; ++j) Wm[j * 6 + k] = (float)V[j][idx[k]];
  }
}

__global__ void v_scale(const float* __restrict__ Bt, const float* __restrict__ Wm,
                        const float* __restrict__ rs, float* __restrict__ V8) {
  __shared__ float Ws[36], rss[6];
  if (threadIdx.x < 36) Ws[threadIdx.x] = Wm[threadIdx.x];
  if (threadIdx.x < 6) rss[threadIdx.x] = rs[threadIdx.x];
  __syncthreads();
  int n = blockIdx.x * 256 + threadIdx.x;
  float b[6];
#pragma unroll
  for (int j = 0; j < 6; ++j) b[j] = Bt[(size_t)n * 8 + j];
#pragma unroll
  for (int k = 0; k < 6; ++k) {
    float s = 0.f;
#pragma unroll
    for (int j = 0; j < 6; ++j) s += b[j] * Ws[j * 6 + k];
    V8[(size_t)n * 8 + k] = s * rss[k];
  }
  V8[(size_t)n * 8 + 6] = 0.f;
  V8[(size_t)n * 8 + 7] = 0.f;
}

// ---------------------------------------------------------------------------
__global__ void pad8c(const float* __restrict__ src, float* __restrict__ dst,
                      float* __restrict__ SC, int sum_idx) {
  int n = blockIdx.x * 256 + threadIdx.x;
  float vals[6];
#pragma unroll
  for (int k = 0; k < 6; ++k) {
    vals[k] = src[(size_t)n * 6 + k];
    dst[(size_t)n * 8 + k] = vals[k];
  }
  dst[(size_t)n * 8 + 6] = 0.f;
  dst[(size_t)n * 8 + 7] = 0.f;
  float* tot = blk_sums(vals, 6);
  if (threadIdx.x == 0)
    for (int c = 0; c < 6; ++c) atomicAdd(&SC[sum_idx + c], tot[c]);
}

__global__ void pack3c(const float* __restrict__ V8, float* __restrict__ W,
                       float* __restrict__ SC, int sum_idx) {
  int n = blockIdx.x * 256 + threadIdx.x;
  float vals[3];
#pragma unroll
  for (int k = 0; k < 3; ++k) {
    vals[k] = V8[(size_t)n * 8 + k];
    W[(size_t)n * 4 + k] = vals[k];
  }
  W[(size_t)n * 4 + 3] = 0.f;
  float* tot = blk_sums(vals, 3);
  if (threadIdx.x == 0)
    for (int c = 0; c < 3; ++c) atomicAdd(&SC[sum_idx + c], tot[c]);
}

__global__ void build_Wc(float* __restrict__ out, int FCpad, int nterms, int nu,
                         const float* __restrict__ base, int bstride, int boff,
                         const float* __restrict__ U, const float* __restrict__ SCin,
                         int rs_idx, float* __restrict__ SC, int sum_idx) {
  int n = blockIdx.x * 256 + threadIdx.x;
  float bv = base[(size_t)n * bstride + boff];
  if (rs_idx >= 0) bv *= rsqrtf(SCin[rs_idx]);
  float uv[3];
  for (int b = 0; b < 3; ++b) uv[b] = (b < nu) ? U[(size_t)b * N + n] : 0.f;
  float vals[8];
  for (int t = 0; t < FCpad; ++t) {
    float v = 0.f;
    if (t < nterms) {
      v = bv;
      for (int b = 0; b < nu; ++b)
        if ((t >> b) & 1) v *= uv[b];
    }
    out[(size_t)n * FCpad + t] = v;
    vals[t] = v;
  }
  float* tot = blk_sums(vals, nterms);
  if (threadIdx.x == 0)
    for (int c = 0; c < nterms; ++c) atomicAdd(&SC[sum_idx + c], tot[c]);
}

__global__ void combine_sq(float* __restrict__ y, const float* __restrict__ Y,
                           int FCpad, int nterms, int nu, const float* __restrict__ U,
                           float* __restrict__ SC, int ssq_idx) {
  int n = blockIdx.x * 256 + threadIdx.x;
  float uv[3];
  for (int b = 0; b < 3; ++b) uv[b] = (b < nu) ? U[(size_t)b * N + n] : 0.f;
  float s = 0.f;
  for (int t = 0; t < nterms; ++t) {
    float w = Y[(size_t)n * FCpad + t];
    int pc = 0;
    for (int b = 0; b < nu; ++b)
      if ((t >> b) & 1) { w *= uv[b]; ++pc; }
    s += (pc & 1) ? -w : w;
  }
  y[n] = s;
  float v = s * s;
  float* tot = blk_sums(&v, 1);
  if (threadIdx.x == 0) atomicAdd(&SC[ssq_idx], tot[0]);
}

__global__ void axpy_sq(float* __restrict__ out, const float* __restrict__ Y, int stride,
                        int off, const float* __restrict__ q0, const float* __restrict__ q1,
                        const float* __restrict__ q2, float* __restrict__ SC,
                        int c0, int c1, int c2, int np, int coef_rs, int out_rs,
                        int ssq_idx) {
  int n = blockIdx.x * 256 + threadIdx.x;
  float crs = (coef_rs >= 0) ? rsqrtf(SC[coef_rs]) : 1.f;
  float s = Y[(size_t)n * stride + off];
  if (np > 0) s -= SC[c0] * crs * q0[n];
  if (np > 1) s -= SC[c1] * crs * q1[n];
  if (np > 2) s -= SC[c2] * crs * q2[n];
  if (out_rs >= 0) s *= rsqrtf(SC[out_rs]);
  out[n] = s;
  if (ssq_idx >= 0) {
    float v = s * s;
    float* tot = blk_sums(&v, 1);
    if (threadIdx.x == 0) atomicAdd(&SC[ssq_idx], tot[0]);
  }
}

__global__ void bprep(const float* __restrict__ V8, int k, const float* __restrict__ Uv,
                      int nd, float* __restrict__ W8, float* __restrict__ SC,
                      int sum_idx, int dot_idx) {
  int n = blockIdx.x * 256 + threadIdx.x;
  float v = V8[(size_t)n * 8 + k];
  W8[(size_t)n * 4 + 0] = v;
  W8[(size_t)n * 4 + 1] = 0.f;
  W8[(size_t)n * 4 + 2] = 0.f;
  W8[(size_t)n * 4 + 3] = 0.f;
  float vals[4];
  vals[0] = v;
  for (int t = 0; t < 3; ++t) vals[1 + t] = (t < nd) ? Uv[(size_t)t * N + n] * v : 0.f;
  float* tot = blk_sums(vals, 1 + nd);
  if (threadIdx.x == 0) {
    atomicAdd(&SC[sum_idx], tot[0]);
    for (int t = 0; t < nd; ++t) atomicAdd(&SC[dot_idx + t], tot[1 + t]);
  }
}

__global__ void vdot_dp(const float* __restrict__ y, const float* __restrict__ Pv,
                        const float* __restrict__ Uv, int nd, float* __restrict__ SC,
                        int dp) {
  int n = blockIdx.x * 256 + threadIdx.x;
  float yv = y[n];
  float vals[6];
  for (int t = 0; t < 3; ++t) {
    if (t < nd) {
      vals[2 * t] = yv * Pv[(size_t)t * N + n];
      vals[2 * t + 1] = Uv[(size_t)t * N + n] * yv;
    } else { vals[2 * t] = 0.f; vals[2 * t + 1] = 0.f; }
  }
  float* tot = blk_sums(vals, 2 * nd);
  if (threadIdx.x == 0)
    for (int i = 0; i < 2 * nd; ++i) atomicAdd(&SC[dp + i], tot[i]);
}

__global__ void vscale1(float* __restrict__ out, const float* __restrict__ in,
                        int stride, int off, const float* __restrict__ SC, int rs_idx) {
  int n = blockIdx.x * 256 + threadIdx.x;
  float v = in[(size_t)n * stride + off];
  if (rs_idx >= 0) v *= rsqrtf(SC[rs_idx]);
  out[n] = v;
}

__global__ void nuc_accum(float* __restrict__ SC, int mode, int z0, int nterms,
                          int ny0, int dps, int nd) {
  if (threadIdx.x || blockIdx.x) return;
  float add = 0.f;
  if (mode == 0) {
    for (int k = 0; k < 3; ++k) add += sqrtf(fabsf(SC[z0 + k] / SC[ny0 + k]));
  } else if (mode == 1) {
    float vmv = 0.f;
    for (int t = 0; t < nterms; ++t) {
      int pc = __popc(t);
      vmv += (pc & 1) ? -SC[z0 + t] : SC[z0 + t];
    }
    add = sqrtf(fabsf(vmv / SC[ny0]));
  } else {
    float vmv = SC[z0];
    for (int t = 0; t < nd; ++t) vmv -= SC[dps + 2 * t] * SC[dps + 2 * t + 1];
    add = sqrtf(fabsf(vmv / SC[ny0]));
  }
  SC[5] += add;
}

__global__ void finalize_k(const float* __restrict__ SC, float* __restrict__ out) {
  if (threadIdx.x || blockIdx.x) return;
  const float Ef = (float)EDG;
  float m1 = SC[0] / Ef, v1 = SC[1] / Ef - m1 * m1;
  float m2 = SC[2] / Ef, v2 = SC[3] / Ef - m2 * m2;
  out[131072] = 0.01f * (v1 + v2) + 0.01f * SC[5];
  out[393217] = SC[4] / (float)N;
}

// ---------------------------------------------------------------------------
extern "C" void kernel_launch(void* const* d_in, const int* in_sizes, int n_in,
                              void* d_out, int out_size, void* d_ws, size_t ws_size,
                              hipStream_t stream) {
  const float* x      = (const float*)d_in[0];
  const int*   ei     = (const int*)  d_in[1];
  const float* gcn1_w = (const float*)d_in[2];
  const float* gcn1_b = (const float*)d_in[3];
  const float* gcn2_w = (const float*)d_in[4];
  const float* gcn2_b = (const float*)d_in[5];
  const float* p1w1   = (const float*)d_in[6];
  const float* p1b1   = (const float*)d_in[7];
  const float* p1w2   = (const float*)d_in[8];
  const float* p1b2   = (const float*)d_in[9];
  const float* p2w1   = (const float*)d_in[10];
  const float* p2b1   = (const float*)d_in[11];
  const float* p2w2   = (const float*)d_in[12];
  const float* p2b2   = (const float*)d_in[13];
  const float* omega1 = (const float*)d_in[14];
  const float* omega2 = (const float*)d_in[15];
  float* out = (float*)d_out;

  float* ws = (float*)d_ws;
  size_t o = 0;
  auto alloc = [&](size_t nf) { float* p = ws + o; o += nf; return p; };
  float* xw1  = alloc((size_t)N * 64);
  float* h1   = alloc((size_t)N * 64);
  float* x1   = alloc((size_t)N * 64);
  float* P    = alloc((size_t)N * 64);
  float* x1w  = alloc((size_t)N * 32);
  float* h2   = alloc((size_t)N * 16);
  float* dis1 = alloc(N);
  float* dis2 = alloc(N);
  float* Qb8  = alloc((size_t)N * 8);
  float* Zi8  = alloc((size_t)N * 8);
  float* Bt8  = alloc((size_t)N * 8);
  float* V8   = alloc((size_t)N * 8);
  float* W8   = alloc((size_t)N * 8);
  float* T8   = alloc((size_t)N * 8);
  float* Y8   = alloc((size_t)N * 8);
  float* Zz8  = alloc((size_t)N * 8);
  float* P8   = alloc((size_t)N * 8);
  float* yv   = alloc(N);
  float* Uv   = alloc((size_t)3 * N);
  float* Pv   = alloc((size_t)3 * N);
  float* SMF  = alloc(64);
  int* rowptr = (int*)alloc(2 * (N + 1) + 2);
  int* cur    = (int*)alloc(2 * N);
  int* col_s  = (int*)alloc(EDG);
  int* perm_s = (int*)alloc(EDG);
  int* col_d  = (int*)alloc(EDG);
  int* perm_d = (int*)alloc(EDG);
  float* w1s  = alloc(EDG);
  float* w1d  = alloc(EDG);
  float* w2s  = alloc(EDG);
  float* w2d  = alloc(EDG);
  // zeroed block: Gd (12 gram slots x 24 doubles) | cnt | deg1 | deg2 | SC
  o = (o + 1) & ~(size_t)1;
  float* zb = ws + o;
  double* Gd = (double*)zb;            o += 288 * 2;
  int* cnt   = (int*)(ws + o);         o += 2 * N;
  float* deg1 = alloc(N);
  float* deg2 = alloc(N);
  float* SC   = alloc(1024);
  const size_t zero_bytes = (576 + 2 * N + 2 * N + 1024) * sizeof(float);
  if (ws_size < o * sizeof(float)) return;

  const int* rp_s = rowptr;
  const int* rp_d = rowptr + (N + 1);

  int cs = 8;
  auto NS = [&]() { int s = cs; cs += 8; return s; };
  int gslot = 0;
  auto NG = [&]() { int g = gslot; gslot += 24; return g; };

  auto run_svd = [&](const float* wsc, const float* wdc, const float* omega) {
    int s0 = NS();
    pad8c<<<16, 256, 0, stream>>>(omega, W8, SC, s0);
    spmm<8, 0><<<1024, 256, 0, stream>>>(rp_s, col_s, wsc, W8, nullptr, Qb8, SC, s0, GEPS, -1, -1);
    int g0 = NG();
    gram16<<<16, 256, 0, stream>>>(Qb8, Gd + g0);
    int sq = NS();
    chol_apply<<<16, 256, 0, stream>>>(Qb8, Gd + g0, SC, sq);
    for (int itp = 0; itp < 2; ++itp) {
      spmm<8, 0><<<1024, 256, 0, stream>>>(rp_d, col_d, wdc, Qb8, nullptr, Zi8, SC, sq, GEPS, -1, -1);
      int g1 = NG();
      gram16<<<16, 256, 0, stream>>>(Zi8, Gd + g1);
      int sz = NS();
      chol_apply<<<16, 256, 0, stream>>>(Zi8, Gd + g1, SC, sz);
      spmm<8, 0><<<1024, 256, 0, stream>>>(rp_s, col_s, wsc, Zi8, nullptr, Qb8, SC, sz, GEPS, -1, -1);
      int g2 = NG();
      gram16<<<16, 256, 0, stream>>>(Qb8, Gd + g2);
      sq = NS();
      chol_apply<<<16, 256, 0, stream>>>(Qb8, Gd + g2, SC, sq);
    }
    spmm<8, 0><<<1024, 256, 0, stream>>>(rp_d, col_d, wdc, Qb8, nullptr, Bt8, SC, sq, GEPS, -1, -1);
    int gb = NG();
    gram16<<<16, 256, 0, stream>>>(Bt8, Gd + gb);
    jacobi6<<<1, 1, 0, stream>>>(Gd + gb, SMF, SMF + 36);
    v_scale<<<16, 256, 0, stream>>>(Bt8, SMF, SMF + 36, V8);
  };

  auto nuc_batch3 = [&](const float* wsc, const float* wdc, int& nyOut) {
    int sW = NS();
    pack3c<<<16, 256, 0, stream>>>(V8, W8, SC, sW);
    int sT = NS();
    spmm<4, 0><<<1024, 256, 0, stream>>>(rp_d, col_d, wdc, W8, nullptr, T8, SC, sW, GEPS, sT, -1);
    int sY = NS(), ny = NS();
    spmm<4, 0><<<1024, 256, 0, stream>>>(rp_s, col_s, wsc, T8, nullptr, Y8, SC, sT, GEPS, sY, ny);
    int zz = NS();
    spmm<4, 0><<<1024, 256, 0, stream>>>(rp_d, col_d, wdc, Y8, nullptr, Zz8, SC, sY, GEPS, -1, zz);
    nuc_accum<<<1, 1, 0, stream>>>(SC, 0, zz, 3, ny, 0, 0);
    vscale1<<<16, 256, 0, stream>>>(Uv, Y8, 4, 2, SC, ny + 2);
    nyOut = ny;
  };

  // ===================== init + CSR =====================
  hipMemsetAsync(zb, 0, zero_bytes, stream);
  hist_edges<<<512, 256, 0, stream>>>(ei, cnt);
  scan2x<<<2, 256, 0, stream>>>(cnt, rowptr, cur);
  scatter_edges<<<512, 256, 0, stream>>>(ei, cur, col_s, perm_s, col_d, perm_d);

  // ===================== layer 1 =====================
  gemm512<<<256, 256, 0, stream>>>(x, p1w1, gcn1_w, xw1, h1);
  edge_gate1<<<2048, 256, 0, stream>>>(xw1, ei, p1b1, p1w2, p1b2,
                                       out + 131073, deg1, SC + 0);
  gather_w2<<<512, 256, 0, stream>>>(out + 131073, perm_s, perm_d, w1s, w1d);
  make_dis<<<16, 256, 0, stream>>>(deg1, dis1);
  spmm<64, 1><<<1024, 256, 0, stream>>>(rp_d, col_d, w1d, h1, dis1, P, SC, -1, 0.f, -1, -1);
  conv_epi64<<<1024, 256, 0, stream>>>(P, h1, dis1, gcn1_b, x1);

  // ===================== SVD1 + nuc1 (elementwise deflation) ==========
  run_svd(w1s, w1d, omega1);
  int nyA;
  nuc_batch3(w1s, w1d, nyA);
  for (int k = 3; k <= 5; ++k) {
    int nu = k - 2, nt = 1 << nu;
    int sW = NS(), sT = NS();
    if (k < 5) {
      build_Wc<<<16, 256, 0, stream>>>(W8, 4, nt, nu, V8, 8, k, Uv, SC, -1, SC, sW);
      spmm<4, 0><<<1024, 256, 0, stream>>>(rp_d, col_d, w1d, W8, nullptr, T8, SC, sW, GEPS, sT, -1);
      spmm<4, 0><<<1024, 256, 0, stream>>>(rp_s, col_s, w1s, T8, nullptr, Y8, SC, sT, GEPS, -1, -1);
      int ny = NS();
      combine_sq<<<16, 256, 0, stream>>>(yv, Y8, 4, nt, nu, Uv, SC, ny);
      int sW2 = NS();
      build_Wc<<<16, 256, 0, stream>>>(W8, 4, nt, nu, yv, 1, 0, Uv, SC, -1, SC, sW2);
      int zz = NS();
      spmm<4, 0><<<1024, 256, 0, stream>>>(rp_d, col_d, w1d, W8, nullptr, Zz8, SC, sW2, GEPS, -1, zz);
      nuc_accum<<<1, 1, 0, stream>>>(SC, 1, zz, nt, ny, 0, 0);
      vscale1<<<16, 256, 0, stream>>>(Uv + (size_t)(k - 2) * N, yv, 1, 0, SC, ny);
    } else {
      build_Wc<<<16, 256, 0, stream>>>(W8, 8, nt, nu, V8, 8, k, Uv, SC, -1, SC, sW);
      spmm<8, 0><<<1024, 256, 0, stream>>>(rp_d, col_d, w1d, W8, nullptr, T8, SC, sW, GEPS, sT, -1);
      spmm<8, 0><<<1024, 256, 0, stream>>>(rp_s, col_s, w1s, T8, nullptr, Y8, SC, sT, GEPS, -1, -1);
      int ny = NS();
      combine_sq<<<16, 256, 0, stream>>>(yv, Y8, 8, nt, nu, Uv, SC, ny);
      int sW2 = NS();
      build_Wc<<<16, 256, 0, stream>>>(W8, 8, nt, nu, yv, 1, 0, Uv, SC, -1, SC, sW2);
      int zz = NS();
      spmm<8, 0><<<1024, 256, 0, stream>>>(rp_d, col_d, w1d, W8, nullptr, Zz8, SC, sW2, GEPS, -1, zz);
      nuc_accum<<<1, 1, 0, stream>>>(SC, 1, zz, nt, ny, 0, 0);
    }
  }

  // ===================== layer 2 + outputs =====================
  gemm64<<<128, 256, 0, stream>>>(x1, p2w1, gcn2_w, x1w, h2);
  edge_gate2<<<1024, 256, 0, stream>>>(x1w, ei, p2b1, p2w2, p2b2,
                                       out + 262145, deg2, SC + 2);
  gather_w2<<<512, 256, 0, stream>>>(out + 262145, perm_s, perm_d, w2s, w2d);
  make_dis<<<16, 256, 0, stream>>>(deg2, dis2);
  spmm<16, 1><<<1024, 256, 0, stream>>>(rp_d, col_d, w2d, h2, dis2, P, SC, -1, 0.f, -1, -1);
  conv2_softmax<<<16, 256, 0, stream>>>(P, h2, dis2, gcn2_b, out, out + 65536, SC);

  // ===================== SVD2 + nuc2 (rank-1 deflation) ==========
  run_svd(w2s, w2d, omega2);
  int nyB;
  nuc_batch3(w2s, w2d, nyB);
  {
    int sWp = NS();
    build_Wc<<<16, 256, 0, stream>>>(W8, 4, 1, 0, Zz8, 4, 2, nullptr, SC, nyB + 2, SC, sWp);
    spmm<4, 0><<<1024, 256, 0, stream>>>(rp_s, col_s, w2s, W8, nullptr, P8, SC, sWp, GEPS, -1, -1);
    vscale1<<<16, 256, 0, stream>>>(Pv, P8, 4, 0, SC, -1);
  }
  for (int k = 3; k <= 5; ++k) {
    int nd = k - 2;
    int C = NS(), sW = NS(), sT = NS(), ny = NS(), sW2 = NS(), zz = NS(), dp = NS();
    bprep<<<16, 256, 0, stream>>>(V8, k, Uv, nd, W8, SC, sW, C);
    spmm<4, 0><<<1024, 256, 0, stream>>>(rp_d, col_d, w2d, W8, nullptr, T8, SC, sW, GEPS, sT, -1);
    spmm<4, 0><<<1024, 256, 0, stream>>>(rp_s, col_s, w2s, T8, nullptr, Y8, SC, sT, GEPS, -1, -1);
    axpy_sq<<<16, 256, 0, stream>>>(yv, Y8, 4, 0, Pv, Pv + N, Pv + 2 * N,
                                    SC, C, C + 1, C + 2, nd, -1, -1, ny);
    build_Wc<<<16, 256, 0, stream>>>(W8, 4, 1, 0, yv, 1, 0, nullptr, SC, -1, SC, sW2);
    spmm<4, 0><<<1024, 256, 0, stream>>>(rp_d, col_d, w2d, W8, nullptr, Zz8, SC, sW2, GEPS, -1, zz);
    vdot_dp<<<16, 256, 0, stream>>>(yv, Pv, Uv, nd, SC, dp);
    nuc_accum<<<1, 1, 0, stream>>>(SC, 2, zz, 0, ny, dp, nd);
    if (k < 5) {
      vscale1<<<16, 256, 0, stream>>>(Uv + (size_t)(k - 2) * N, yv, 1, 0, SC, ny);
      int sW3 = NS();
      build_Wc<<<16, 256, 0, stream>>>(W8, 4, 1, 0, Zz8, 4, 0, nullptr, SC, ny, SC, sW3);
      spmm<4, 0><<<1024, 256, 0, stream>>>(rp_s, col_s, w2s, W8, nullptr, P8, SC, sW3, GEPS, -1, -1);
      axpy_sq<<<16, 256, 0, stream>>>(Pv + (size_t)(k - 2) * N, P8, 4, 0,
                                      Pv, Pv + N, Pv + 2 * N,
                                      SC, dp + 1, dp + 3, dp + 5, nd, ny, -1, -1);
    }
  }

  finalize_k<<<1, 1, 0, stream>>>(SC, out);
}

// Round 5
// 863.410 us; speedup vs baseline: 4.6688x; 1.3958x over previous
//
#include <hip/hip_runtime.h>
#include <cmath>

constexpr int N = 4096;
constexpr int EDG = 131072;
constexpr float GEPS = 1e-6f;

// ---------------------------------------------------------------------------
// block-wide reduction helper: sums vals[0..cnt-1] over 256 threads.
__device__ __forceinline__ float* blk_sums(float* vals, int cnt) {
  __shared__ float part[4][16];
  __shared__ float tot[16];
  const int lane = threadIdx.x & 63, wv = threadIdx.x >> 6;
  for (int c = 0; c < cnt; ++c) {
    float v = vals[c];
    for (int off = 32; off; off >>= 1) v += __shfl_down(v, off);
    if (lane == 0) part[wv][c] = v;
  }
  __syncthreads();
  if (threadIdx.x == 0)
    for (int c = 0; c < cnt; ++c)
      tot[c] = part[0][c] + part[1][c] + part[2][c] + part[3][c];
  __syncthreads();
  return tot;
}

// ---------------------------------------------------------------------------
// CSR build
__global__ void hist_edges(const int* __restrict__ ei, int* __restrict__ cnt) {
  int e = blockIdx.x * 256 + threadIdx.x;
  atomicAdd(&cnt[ei[e]], 1);
  atomicAdd(&cnt[N + ei[EDG + e]], 1);
}

__global__ __launch_bounds__(256) void scan2x(const int* __restrict__ cnt,
                                              int* __restrict__ rowptr,
                                              int* __restrict__ cur) {
  const int b = blockIdx.x;
  const int* c = cnt + b * N;
  int* rp = rowptr + b * (N + 1);
  int* cu = cur + b * N;
  __shared__ int part[256];
  const int t = threadIdx.x;
  int local[16], s = 0;
  const int base = t * 16;
  for (int i = 0; i < 16; ++i) { local[i] = s; s += c[base + i]; }
  part[t] = s;
  __syncthreads();
  if (t == 0) {
    int acc = 0;
    for (int i = 0; i < 256; ++i) { int v = part[i]; part[i] = acc; acc += v; }
  }
  __syncthreads();
  const int off = part[t];
  for (int i = 0; i < 16; ++i) { rp[base + i] = off + local[i]; cu[base + i] = off + local[i]; }
  if (t == 255) rp[N] = off + s;
}

__global__ void scatter_edges(const int* __restrict__ ei, int* __restrict__ cur,
                              int* __restrict__ col_s, int* __restrict__ perm_s,
                              int* __restrict__ col_d, int* __restrict__ perm_d) {
  int e = blockIdx.x * 256 + threadIdx.x;
  int s = ei[e], d = ei[EDG + e];
  int ps = atomicAdd(&cur[s], 1);
  col_s[ps] = d; perm_s[ps] = e;
  int pd = atomicAdd(&cur[N + d], 1);
  col_d[pd] = s; perm_d[pd] = e;
}

__global__ void gather_w2(const float* __restrict__ s, const int* __restrict__ perm_s,
                          const int* __restrict__ perm_d, float* __restrict__ ws_,
                          float* __restrict__ wd_) {
  int p = blockIdx.x * 256 + threadIdx.x;
  ws_[p] = s[perm_s[p]];
  wd_[p] = s[perm_d[p]];
}

// ---------------------------------------------------------------------------
// single-graph SpMM (conv layers + layer-B p-passes)
template<int F, int DIS>
__global__ __launch_bounds__(256) void spmm(const int* __restrict__ rowptr,
                                            const int* __restrict__ col,
                                            const float* __restrict__ w,
                                            const float* __restrict__ X,
                                            const float* __restrict__ dis,
                                            float* __restrict__ OUT,
                                            float* __restrict__ SC, int cs_idx,
                                            float eps, int osum, int ossq) {
  constexpr int ES = 64 / F;
  const int lane = threadIdx.x & 63;
  const int wv = threadIdx.x >> 6;
  const int f = lane & (F - 1);
  const int es = lane / F;
  const int r = blockIdx.x * 4 + wv;
  const int e0 = rowptr[r], e1 = rowptr[r + 1];
  float acc = 0.f;
  for (int e = e0 + es; e < e1; e += ES) {
    int c = col[e];
    float wx = w[e];
    if (DIS) wx *= dis[c];
    acc += wx * X[(size_t)c * F + f];
  }
#pragma unroll
  for (int off = F; off < 64; off <<= 1) acc += __shfl_xor(acc, off);
  float o = acc + ((cs_idx >= 0) ? eps * SC[cs_idx + f] : 0.f);
  if (es == 0) OUT[(size_t)r * F + f] = o;
  if (osum >= 0 || ossq >= 0) {
    __shared__ float bs[8], bq[8];
    if (threadIdx.x < F) { bs[threadIdx.x] = 0.f; bq[threadIdx.x] = 0.f; }
    __syncthreads();
    if (es == 0) {
      if (osum >= 0) atomicAdd(&bs[f], o);
      if (ossq >= 0) atomicAdd(&bq[f], o * o);
    }
    __syncthreads();
    if (threadIdx.x < F) {
      if (osum >= 0) atomicAdd(&SC[osum + threadIdx.x], bs[threadIdx.x]);
      if (ossq >= 0) atomicAdd(&SC[ossq + threadIdx.x], bq[threadIdx.x]);
    }
  }
}

// Batched two-graph SpMM: lanes 0-31 graph A (width FA), 32-63 graph B (FB).
template<int FA, int FB>
__global__ __launch_bounds__(256) void spmm2(const int* __restrict__ rowptr,
                                             const int* __restrict__ col,
                                             const float* __restrict__ wA,
                                             const float* __restrict__ wB,
                                             const float* __restrict__ XA,
                                             const float* __restrict__ XB,
                                             float* __restrict__ OA,
                                             float* __restrict__ OB,
                                             float* __restrict__ SC,
                                             int csA, int csB, float eps,
                                             int osumA, int ossqA, int osumB, int ossqB) {
  const int lane = threadIdx.x & 63;
  const int wv = threadIdx.x >> 6;
  const int half = lane >> 5;
  const int la = lane & 31;
  const int F = half ? FB : FA;
  const int f = la & (F - 1);
  const int es = la / F;
  const int ES = 32 / F;
  const int r = blockIdx.x * 4 + wv;
  const int e0 = rowptr[r], e1 = rowptr[r + 1];
  const float* w = half ? wB : wA;
  const float* X = half ? XB : XA;
  float acc = 0.f;
  for (int e = e0 + es; e < e1; e += ES)
    acc += w[e] * X[(size_t)col[e] * F + f];
  for (int off = F; off < 32; off <<= 1) acc += __shfl_xor(acc, off);
  const int cs = half ? csB : csA;
  float o = acc + ((cs >= 0) ? eps * SC[cs + f] : 0.f);
  if (es == 0) {
    float* O = half ? OB : OA;
    O[(size_t)r * F + f] = o;
  }
  if (osumA >= 0 || ossqA >= 0 || osumB >= 0 || ossqB >= 0) {
    __shared__ float bs[2][8], bq[2][8];
    if (threadIdx.x < 16) { bs[threadIdx.x >> 3][threadIdx.x & 7] = 0.f;
                            bq[threadIdx.x >> 3][threadIdx.x & 7] = 0.f; }
    __syncthreads();
    const int osum = half ? osumB : osumA, ossq = half ? ossqB : ossqA;
    if (es == 0) {
      if (osum >= 0) atomicAdd(&bs[half][f], o);
      if (ossq >= 0) atomicAdd(&bq[half][f], o * o);
    }
    __syncthreads();
    if (threadIdx.x < 16) {
      int h = threadIdx.x >> 3, ff = threadIdx.x & 7;
      int os_ = h ? osumB : osumA, oq_ = h ? ossqB : ossqA;
      int Fh = h ? FB : FA;
      if (os_ >= 0 && ff < Fh) atomicAdd(&SC[os_ + ff], bs[h][ff]);
      if (oq_ >= 0 && ff < Fh) atomicAdd(&SC[oq_ + ff], bq[h][ff]);
    }
  }
}

// ---------------------------------------------------------------------------
// Fused layer-1 GEMM: O1 = A@W1, O2 = A@W2.  A[4096,512], W*[512,64].
__global__ __launch_bounds__(256) void gemm512(const float* __restrict__ A,
                                               const float* __restrict__ W1,
                                               const float* __restrict__ W2,
                                               float* __restrict__ O1,
                                               float* __restrict__ O2) {
  __shared__ float As[16][33];
  __shared__ float Ws[32][128];
  const int t = threadIdx.x;
  const int r = t >> 4;
  const int cg = t & 15;
  const int r0 = blockIdx.x * 16;
  float acc[8];
#pragma unroll
  for (int j = 0; j < 8; ++j) acc[j] = 0.f;
  for (int k0 = 0; k0 < 512; k0 += 32) {
    __syncthreads();
    {
      int idx = t;
#pragma unroll
      for (int i = 0; i < 2; ++i, idx += 256) {
        int rr = idx >> 5, kk = idx & 31;
        As[rr][kk] = A[(size_t)(r0 + rr) * 512 + k0 + kk];
      }
    }
    for (int idx = t; idx < 32 * 128; idx += 256) {
      int kk = idx >> 7, c = idx & 127;
      Ws[kk][c] = (c < 64) ? W1[(size_t)(k0 + kk) * 64 + c]
                           : W2[(size_t)(k0 + kk) * 64 + c - 64];
    }
    __syncthreads();
#pragma unroll 4
    for (int kk = 0; kk < 32; ++kk) {
      float a = As[r][kk];
      const float* wr = &Ws[kk][cg * 8];
#pragma unroll
      for (int j = 0; j < 8; ++j) acc[j] += a * wr[j];
    }
  }
  int n = r0 + r;
  if (cg < 8) {
#pragma unroll
    for (int j = 0; j < 8; ++j) O1[(size_t)n * 64 + cg * 8 + j] = acc[j];
  } else {
#pragma unroll
    for (int j = 0; j < 8; ++j) O2[(size_t)n * 64 + (cg - 8) * 8 + j] = acc[j];
  }
}

// Fused layer-2 GEMM: O1[4096,32]=A@W1, O2[4096,16]=A@W2. A[4096,64].
__global__ __launch_bounds__(256) void gemm64(const float* __restrict__ A,
                                              const float* __restrict__ W1,
                                              const float* __restrict__ W2,
                                              float* __restrict__ O1,
                                              float* __restrict__ O2) {
  __shared__ float As[32][65];
  __shared__ float Ws[64][48];
  const int t = threadIdx.x;
  const int r = t >> 3;
  const int cg = t & 7;
  const int r0 = blockIdx.x * 32;
  for (int idx = t; idx < 32 * 64; idx += 256)
    As[idx >> 6][idx & 63] = A[(size_t)(r0 + (idx >> 6)) * 64 + (idx & 63)];
  for (int idx = t; idx < 64 * 48; idx += 256) {
    int kk = idx / 48, c = idx % 48;
    Ws[kk][c] = (c < 32) ? W1[kk * 32 + c] : W2[kk * 16 + c - 32];
  }
  __syncthreads();
  float acc[6] = {0.f, 0.f, 0.f, 0.f, 0.f, 0.f};
  for (int k = 0; k < 64; ++k) {
    float a = As[r][k];
#pragma unroll
    for (int j = 0; j < 6; ++j) acc[j] += a * Ws[k][cg + 8 * j];
  }
  int n = r0 + r;
#pragma unroll
  for (int j = 0; j < 6; ++j) {
    int c = cg + 8 * j;
    if (c < 32) O1[(size_t)n * 32 + c] = acc[j];
    else O2[(size_t)n * 16 + c - 32] = acc[j];
  }
}

// ---------------------------------------------------------------------------
__global__ void edge_gate1(const float* __restrict__ xw, const int* __restrict__ ei,
                           const float* __restrict__ b1, const float* __restrict__ w2,
                           const float* __restrict__ b2, float* __restrict__ s_out,
                           float* __restrict__ deg, float* __restrict__ SCs) {
  const int lane = threadIdx.x & 63;
  const int wave = threadIdx.x >> 6;
  const float b1v = b1[lane];
  const float w2v = w2[lane];
  const float b2s = b2[0];
  float lsum = 0.f, lssq = 0.f;
  for (int it = 0; it < 16; ++it) {
    const int e = blockIdx.x * 64 + it * 4 + wave;
    const int s = ei[e];
    const int d = ei[EDG + e];
    float g = xw[(size_t)s * 64 + lane] - xw[(size_t)d * 64 + lane] + b1v;
    g = fmaxf(g, 0.f) * w2v;
#pragma unroll
    for (int off = 32; off; off >>= 1) g += __shfl_down(g, off);
    if (lane == 0) {
      float agg = g + b2s;
      agg *= agg;
      float sv = 1.f / (1.f + __expf(-agg));
      s_out[e] = sv;
      atomicAdd(&deg[d], sv);
      lsum += sv; lssq += sv * sv;
    }
  }
  __shared__ float red[8];
  if (lane == 0) { red[wave] = lsum; red[4 + wave] = lssq; }
  __syncthreads();
  if (threadIdx.x == 0) {
    atomicAdd(&SCs[0], red[0] + red[1] + red[2] + red[3]);
    atomicAdd(&SCs[1], red[4] + red[5] + red[6] + red[7]);
  }
}

__global__ void edge_gate2(const float* __restrict__ xw, const int* __restrict__ ei,
                           const float* __restrict__ b1, const float* __restrict__ w2,
                           const float* __restrict__ b2, float* __restrict__ s_out,
                           float* __restrict__ deg, float* __restrict__ SCs) {
  const int half = threadIdx.x & 31;
  const int wi = threadIdx.x >> 5;
  const float b1v = b1[half];
  const float w2v = w2[half];
  const float b2s = b2[0];
  float lsum = 0.f, lssq = 0.f;
  for (int it = 0; it < 16; ++it) {
    const int e = blockIdx.x * 128 + it * 8 + wi;
    const int s = ei[e];
    const int d = ei[EDG + e];
    float g = xw[(size_t)s * 32 + half] - xw[(size_t)d * 32 + half] + b1v;
    g = fmaxf(g, 0.f) * w2v;
#pragma unroll
    for (int off = 16; off; off >>= 1) g += __shfl_down(g, off, 32);
    if (half == 0) {
      float agg = g + b2s;
      agg *= agg;
      float sv = 1.f / (1.f + __expf(-agg));
      s_out[e] = sv;
      atomicAdd(&deg[d], sv);
      lsum += sv; lssq += sv * sv;
    }
  }
  __shared__ float red[16];
  if (half == 0) { red[wi] = lsum; red[8 + wi] = lssq; }
  __syncthreads();
  if (threadIdx.x == 0) {
    float a = 0.f, b = 0.f;
    for (int i = 0; i < 8; ++i) { a += red[i]; b += red[8 + i]; }
    atomicAdd(&SCs[0], a);
    atomicAdd(&SCs[1], b);
  }
}

// ---------------------------------------------------------------------------
__global__ void make_dis(const float* __restrict__ deg, float* __restrict__ dis) {
  int n = blockIdx.x * 256 + threadIdx.x;
  dis[n] = rsqrtf(deg[n] + 1.0f);
}

__global__ void conv_epi64(const float* __restrict__ P, const float* __restrict__ h,
                           const float* __restrict__ dis, const float* __restrict__ bias,
                           float* __restrict__ out) {
  int i = blockIdx.x * 256 + threadIdx.x;
  int n = i >> 6, f = i & 63;
  float d = dis[n];
  float v = d * (P[i] + d * h[i]) + bias[f];
  out[i] = fmaxf(v, 0.f);
}

__global__ void conv2_softmax(const float* __restrict__ P, const float* __restrict__ h,
                              const float* __restrict__ dis, const float* __restrict__ bias,
                              float* __restrict__ ls, float* __restrict__ sm,
                              float* __restrict__ SC) {
  const int t = threadIdx.x;
  const int r = blockIdx.x * 256 + t;
  const float d = dis[r];
  float v[16];
  float mx = -3.0e38f, mx2 = -3.0e38f;
#pragma unroll
  for (int c = 0; c < 16; ++c) {
    v[c] = d * (P[(size_t)r * 16 + c] + d * h[(size_t)r * 16 + c]) + bias[c];
    if (v[c] > mx) { mx2 = mx; mx = v[c]; }
    else if (v[c] > mx2) mx2 = v[c];
  }
  float se = 0.f;
#pragma unroll
  for (int c = 0; c < 16; ++c) se += expf(v[c] - mx);
  const float lse = mx + logf(se);
#pragma unroll
  for (int c = 0; c < 16; ++c) {
    float z = v[c] - lse;
    ls[(size_t)r * 16 + c] = z;
    sm[(size_t)r * 16 + c] = expf(z);
  }
  float calib = mx2 - mx;
  float* tot = blk_sums(&calib, 1);
  if (t == 0) atomicAdd(&SC[4], tot[0]);
}

// ---------------------------------------------------------------------------
// batched gram: 21 packed upper-tri doubles per slab (pre-zeroed slots).
__global__ void gram2(const float* __restrict__ YA, const float* __restrict__ YB,
                      double* __restrict__ GA, double* __restrict__ GB) {
  const int t = threadIdx.x;
  const int lane = t & 63, wv = t >> 6;
  const int n = blockIdx.x * 256 + t;
  float g[42];
  {
    float ya[6], yb[6];
#pragma unroll
    for (int j = 0; j < 6; ++j) { ya[j] = YA[(size_t)n * 8 + j]; yb[j] = YB[(size_t)n * 8 + j]; }
    int p = 0;
#pragma unroll
    for (int i = 0; i < 6; ++i)
#pragma unroll
      for (int j = i; j < 6; ++j) { g[p] = ya[i] * ya[j]; g[21 + p] = yb[i] * yb[j]; ++p; }
  }
#pragma unroll
  for (int p = 0; p < 42; ++p)
    for (int off = 32; off; off >>= 1) g[p] += __shfl_down(g[p], off);
  __shared__ float part[4][42];
  if (lane == 0)
    for (int p = 0; p < 42; ++p) part[wv][p] = g[p];
  __syncthreads();
  if (t < 42) {
    float s = part[0][t] + part[1][t] + part[2][t] + part[3][t];
    if (t < 21) atomicAdd(&GA[t], (double)s);
    else atomicAdd(&GB[t - 21], (double)s);
  }
}

// batched cholesky + R^{-1} apply + colsums of both normalized slabs
__global__ void chol2(float* __restrict__ YA, const double* __restrict__ GA, int csA,
                      float* __restrict__ YB, const double* __restrict__ GB, int csB,
                      float* __restrict__ SC) {
  __shared__ float Rs[2][36];
  if (threadIdx.x < 2) {
    const double* G = threadIdx.x ? GB : GA;
    double Gf[6][6];
    int p = 0;
    for (int i = 0; i < 6; ++i)
      for (int j = i; j < 6; ++j) { Gf[i][j] = G[p]; Gf[j][i] = G[p]; ++p; }
    double Rm[6][6];
    for (int i = 0; i < 6; ++i) for (int j = 0; j < 6; ++j) Rm[i][j] = 0.0;
    for (int j = 0; j < 6; ++j) {
      double s = Gf[j][j];
      for (int k = 0; k < j; ++k) s -= Rm[k][j] * Rm[k][j];
      double dj = sqrt(fmax(s, 1e-30));
      Rm[j][j] = dj;
      for (int i = j + 1; i < 6; ++i) {
        double v = Gf[j][i];
        for (int k = 0; k < j; ++k) v -= Rm[k][j] * Rm[k][i];
        Rm[j][i] = v / dj;
      }
    }
    for (int i = 0; i < 6; ++i)
      for (int j = 0; j < 6; ++j) Rs[threadIdx.x][i * 6 + j] = (float)Rm[i][j];
  }
  __syncthreads();
  int n = blockIdx.x * 256 + threadIdx.x;
  float vals[12];
  {
    float y[6], q[6];
#pragma unroll
    for (int j = 0; j < 6; ++j) y[j] = YA[(size_t)n * 8 + j];
#pragma unroll
    for (int j = 0; j < 6; ++j) {
      float s = y[j];
#pragma unroll
      for (int i = 0; i < 6; ++i)
        if (i < j) s -= q[i] * Rs[0][i * 6 + j];
      q[j] = s / Rs[0][j * 6 + j];
    }
#pragma unroll
    for (int j = 0; j < 6; ++j) { YA[(size_t)n * 8 + j] = q[j]; vals[j] = q[j]; }
  }
  {
    float y[6], q[6];
#pragma unroll
    for (int j = 0; j < 6; ++j) y[j] = YB[(size_t)n * 8 + j];
#pragma unroll
    for (int j = 0; j < 6; ++j) {
      float s = y[j];
#pragma unroll
      for (int i = 0; i < 6; ++i)
        if (i < j) s -= q[i] * Rs[1][i * 6 + j];
      q[j] = s / Rs[1][j * 6 + j];
    }
#pragma unroll
    for (int j = 0; j < 6; ++j) { YB[(size_t)n * 8 + j] = q[j]; vals[6 + j] = q[j]; }
  }
  float* tot = blk_sums(vals, 12);
  if (threadIdx.x == 0)
    for (int j = 0; j < 6; ++j) {
      atomicAdd(&SC[csA + j], tot[j]);
      atomicAdd(&SC[csB + j], tot[6 + j]);
    }
}

// batched wave-parallel 6x6 Jacobi eigensolver (wave 0 -> A, wave 1 -> B).
__global__ __launch_bounds__(128) void jacobi2(const double* __restrict__ GA,
                                               const double* __restrict__ GB,
                                               float* __restrict__ SMFA,
                                               float* __restrict__ SMFB) {
  const int wv = threadIdx.x >> 6;
  const int lane = threadIdx.x & 63;
  const double* G = wv ? GB : GA;
  float* SMF = wv ? SMFB : SMFA;
  double a[6], v[6];
#pragma unroll
  for (int j = 0; j < 6; ++j) { a[j] = 0.0; v[j] = 0.0; }
  if (lane < 6) {
    const int r = lane;
    for (int j = 0; j < 6; ++j) {
      int i0 = r < j ? r : j, j0 = r < j ? j : r;
      a[j] = G[i0 * 6 - i0 * (i0 - 1) / 2 + (j0 - i0)];
    }
    v[r] = 1.0;
  }
  for (int sweep = 0; sweep < 10; ++sweep) {
#pragma unroll
    for (int p = 0; p < 5; ++p)
#pragma unroll
      for (int q = p + 1; q < 6; ++q) {
        double apq = __shfl(a[q], p, 64);
        double app = __shfl(a[p], p, 64);
        double aqq = __shfl(a[q], q, 64);
        double c = 1.0, s = 0.0;
        if (fabs(apq) > 1e-300) {
          double tau = (aqq - app) / (2.0 * apq);
          double tt = (tau >= 0.0) ? 1.0 / (tau + sqrt(1.0 + tau * tau))
                                   : 1.0 / (tau - sqrt(1.0 + tau * tau));
          c = 1.0 / sqrt(1.0 + tt * tt); s = tt * c;
        }
        double ap_ = a[p], aq_ = a[q];
        a[p] = c * ap_ - s * aq_;
        a[q] = s * ap_ + c * aq_;
#pragma unroll
        for (int i = 0; i < 6; ++i) {
          double rp = __shfl(a[i], p, 64);
          double rq = __shfl(a[i], q, 64);
          if (lane == p) a[i] = c * rp - s * rq;
          if (lane == q) a[i] = s * rp + c * rq;
        }
        double vp_ = v[p], vq_ = v[q];
        v[p] = c * vp_ - s * vq_;
        v[q] = s * vp_ + c * vq_;
      }
  }
  __shared__ double diag[2][6];
  __shared__ double Vs[2][6][6];
  if (lane < 6) {
    diag[wv][lane] = a[lane];
    for (int j = 0; j < 6; ++j) Vs[wv][lane][j] = v[j];
  }
  __syncthreads();
  if (lane == 0) {
    int idx[6] = {0, 1, 2, 3, 4, 5};
    for (int x = 0; x < 5; ++x)
      for (int b = 0; b < 5 - x; ++b)
        if (diag[wv][idx[b]] < diag[wv][idx[b + 1]]) {
          int tmp = idx[b]; idx[b] = idx[b + 1]; idx[b + 1] = tmp;
        }
    for (int k = 0; k < 6; ++k) {
      double lam = diag[wv][idx[k]];
      SMF[36 + k] = (float)(1.0 / sqrt(fmax(lam, 1e-30)));
      for (int j = 0; j < 6; ++j) SMF[j * 6 + k] = (float)Vs[wv][j][idx[k]];
    }
  }
}

__global__ void v_scale2(const float* __restrict__ BtA, const float* __restrict__ SMFA,
                         const float* __restrict__ BtB, const float* __restrict__ SMFB,
                         float* __restrict__ V8A, float* __restrict__ V8B) {
  __shared__ float WsA[36], rsA[6], WsB[36], rsB[6];
  if (threadIdx.x < 36) { WsA[threadIdx.x] = SMFA[threadIdx.x]; WsB[threadIdx.x] = SMFB[threadIdx.x]; }
  if (threadIdx.x < 6) { rsA[threadIdx.x] = SMFA[36 + threadIdx.x]; rsB[threadIdx.x] = SMFB[36 + threadIdx.x]; }
  __syncthreads();
  int n = blockIdx.x * 256 + threadIdx.x;
  float ba[6], bb[6];
#pragma unroll
  for (int j = 0; j < 6; ++j) { ba[j] = BtA[(size_t)n * 8 + j]; bb[j] = BtB[(size_t)n * 8 + j]; }
#pragma unroll
  for (int k = 0; k < 6; ++k) {
    float sa = 0.f, sb = 0.f;
#pragma unroll
    for (int j = 0; j < 6; ++j) { sa += ba[j] * WsA[j * 6 + k]; sb += bb[j] * WsB[j * 6 + k]; }
    V8A[(size_t)n * 8 + k] = sa * rsA[k];
    V8B[(size_t)n * 8 + k] = sb * rsB[k];
  }
  V8A[(size_t)n * 8 + 6] = 0.f; V8A[(size_t)n * 8 + 7] = 0.f;
  V8B[(size_t)n * 8 + 6] = 0.f; V8B[(size_t)n * 8 + 7] = 0.f;
}

// ---------------------------------------------------------------------------
__global__ void pad8c2(const float* __restrict__ o1, float* __restrict__ d1,
                       const float* __restrict__ o2, float* __restrict__ d2,
                       float* __restrict__ SC, int s1, int s2) {
  int n = blockIdx.x * 256 + threadIdx.x;
  float vals[12];
#pragma unroll
  for (int k = 0; k < 6; ++k) {
    vals[k] = o1[(size_t)n * 6 + k];     d1[(size_t)n * 8 + k] = vals[k];
    vals[6 + k] = o2[(size_t)n * 6 + k]; d2[(size_t)n * 8 + k] = vals[6 + k];
  }
  d1[(size_t)n * 8 + 6] = 0.f; d1[(size_t)n * 8 + 7] = 0.f;
  d2[(size_t)n * 8 + 6] = 0.f; d2[(size_t)n * 8 + 7] = 0.f;
  float* tot = blk_sums(vals, 12);
  if (threadIdx.x == 0)
    for (int c = 0; c < 6; ++c) {
      atomicAdd(&SC[s1 + c], tot[c]);
      atomicAdd(&SC[s2 + c], tot[6 + c]);
    }
}

__global__ void pack3c2(const float* __restrict__ V8A, float* __restrict__ WA,
                        const float* __restrict__ V8B, float* __restrict__ WB,
                        float* __restrict__ SC, int sA, int sB) {
  int n = blockIdx.x * 256 + threadIdx.x;
  float vals[6];
#pragma unroll
  for (int k = 0; k < 3; ++k) {
    vals[k] = V8A[(size_t)n * 8 + k];     WA[(size_t)n * 4 + k] = vals[k];
    vals[3 + k] = V8B[(size_t)n * 8 + k]; WB[(size_t)n * 4 + k] = vals[3 + k];
  }
  WA[(size_t)n * 4 + 3] = 0.f;
  WB[(size_t)n * 4 + 3] = 0.f;
  float* tot = blk_sums(vals, 6);
  if (threadIdx.x == 0)
    for (int c = 0; c < 3; ++c) {
      atomicAdd(&SC[sA + c], tot[c]);
      atomicAdd(&SC[sB + c], tot[3 + c]);
    }
}

// single-graph build (layer-B p-passes)
__global__ void build_Wc(float* __restrict__ out, int FCpad, int nterms, int nu,
                         const float* __restrict__ base, int bstride, int boff,
                         const float* __restrict__ U, const float* __restrict__ SCin,
                         int rs_idx, float* __restrict__ SC, int sum_idx) {
  int n = blockIdx.x * 256 + threadIdx.x;
  float bv = base[(size_t)n * bstride + boff];
  if (rs_idx >= 0) bv *= rsqrtf(SCin[rs_idx]);
  float uv[3];
  for (int b = 0; b < 3; ++b) uv[b] = (b < nu) ? U[(size_t)b * N + n] : 0.f;
  float vals[8];
  for (int t = 0; t < FCpad; ++t) {
    float v = 0.f;
    if (t < nterms) {
      v = bv;
      for (int b = 0; b < nu; ++b)
        if ((t >> b) & 1) v *= uv[b];
    }
    out[(size_t)n * FCpad + t] = v;
    vals[t] = v;
  }
  float* tot = blk_sums(vals, nterms);
  if (threadIdx.x == 0)
    for (int c = 0; c < nterms; ++c) atomicAdd(&SC[sum_idx + c], tot[c]);
}

// batched deflation builds: blocks 0-15 = A rule, 16-31 = B rule (+dots)
__global__ void buildAB(float* __restrict__ WA, int FCpad, int nt, int nu,
                        const float* __restrict__ V8A, int kcol,
                        const float* __restrict__ UvA, float* __restrict__ SC, int sWa,
                        float* __restrict__ WB, const float* __restrict__ V8B,
                        const float* __restrict__ UvB, int nd, int sWb, int Cidx) {
  const int bid = blockIdx.x;
  const int n = (bid & 15) * 256 + threadIdx.x;
  if (bid < 16) {
    float bv = V8A[(size_t)n * 8 + kcol];
    float uv[3];
    for (int b = 0; b < 3; ++b) uv[b] = (b < nu) ? UvA[(size_t)b * N + n] : 0.f;
    float vals[8];
    for (int t = 0; t < FCpad; ++t) {
      float v = 0.f;
      if (t < nt) {
        v = bv;
        for (int b = 0; b < nu; ++b)
          if ((t >> b) & 1) v *= uv[b];
      }
      WA[(size_t)n * FCpad + t] = v;
      vals[t] = v;
    }
    float* tot = blk_sums(vals, nt);
    if (threadIdx.x == 0)
      for (int c = 0; c < nt; ++c) atomicAdd(&SC[sWa + c], tot[c]);
  } else {
    float v = V8B[(size_t)n * 8 + kcol];
    WB[(size_t)n * 4 + 0] = v;
    WB[(size_t)n * 4 + 1] = 0.f;
    WB[(size_t)n * 4 + 2] = 0.f;
    WB[(size_t)n * 4 + 3] = 0.f;
    float vals[4];
    vals[0] = v;
    for (int t = 0; t < 3; ++t) vals[1 + t] = (t < nd) ? UvB[(size_t)t * N + n] * v : 0.f;
    float* tot = blk_sums(vals, 1 + nd);
    if (threadIdx.x == 0) {
      atomicAdd(&SC[sWb], tot[0]);
      for (int t = 0; t < nd; ++t) atomicAdd(&SC[Cidx + t], tot[1 + t]);
    }
  }
}

// batched epilogue: A = signed combine of Y-slab columns; B = axpy + dots
__global__ void epiAB(const float* __restrict__ YA, int FA, int nt, int nu,
                      const float* __restrict__ UvA, float* __restrict__ yvA, int nyA2,
                      const float* __restrict__ YB, const float* __restrict__ Pv,
                      const float* __restrict__ UvB, int nd, float* __restrict__ yvB,
                      int Cidx, int nyB2, int dp, float* __restrict__ SC) {
  const int bid = blockIdx.x;
  const int n = (bid & 15) * 256 + threadIdx.x;
  if (bid < 16) {
    float uv[3];
    for (int b = 0; b < 3; ++b) uv[b] = (b < nu) ? UvA[(size_t)b * N + n] : 0.f;
    float s = 0.f;
    for (int t = 0; t < nt; ++t) {
      float w = YA[(size_t)n * FA + t];
      int pc = 0;
      for (int b = 0; b < nu; ++b)
        if ((t >> b) & 1) { w *= uv[b]; ++pc; }
      s += (pc & 1) ? -w : w;
    }
    yvA[n] = s;
    float v = s * s;
    float* tot = blk_sums(&v, 1);
    if (threadIdx.x == 0) atomicAdd(&SC[nyA2], tot[0]);
  } else {
    float y = YB[(size_t)n * 4];
    for (int t = 0; t < nd; ++t) y -= SC[Cidx + t] * Pv[(size_t)t * N + n];
    yvB[n] = y;
    float vals[7];
    vals[0] = y * y;
    for (int t = 0; t < 3; ++t) {
      vals[1 + 2 * t] = (t < nd) ? y * Pv[(size_t)t * N + n] : 0.f;
      vals[2 + 2 * t] = (t < nd) ? UvB[(size_t)t * N + n] * y : 0.f;
    }
    float* tot = blk_sums(vals, 1 + 2 * nd);
    if (threadIdx.x == 0) {
      atomicAdd(&SC[nyB2], tot[0]);
      for (int i = 0; i < 2 * nd; ++i) atomicAdd(&SC[dp + i], tot[1 + i]);
    }
  }
}

__global__ void buildAB2(float* __restrict__ WA, int FCpad, int nt, int nu,
                         const float* __restrict__ yvA, const float* __restrict__ UvA,
                         int sW2a, float* __restrict__ WB,
                         const float* __restrict__ yvB, int sW2b,
                         float* __restrict__ SC) {
  const int bid = blockIdx.x;
  const int n = (bid & 15) * 256 + threadIdx.x;
  if (bid < 16) {
    float bv = yvA[n];
    float uv[3];
    for (int b = 0; b < 3; ++b) uv[b] = (b < nu) ? UvA[(size_t)b * N + n] : 0.f;
    float vals[8];
    for (int t = 0; t < FCpad; ++t) {
      float v = 0.f;
      if (t < nt) {
        v = bv;
        for (int b = 0; b < nu; ++b)
          if ((t >> b) & 1) v *= uv[b];
      }
      WA[(size_t)n * FCpad + t] = v;
      vals[t] = v;
    }
    float* tot = blk_sums(vals, nt);
    if (threadIdx.x == 0)
      for (int c = 0; c < nt; ++c) atomicAdd(&SC[sW2a + c], tot[c]);
  } else {
    float v = yvB[n];
    WB[(size_t)n * 4 + 0] = v;
    WB[(size_t)n * 4 + 1] = 0.f;
    WB[(size_t)n * 4 + 2] = 0.f;
    WB[(size_t)n * 4 + 3] = 0.f;
    float vv = v;
    float* tot = blk_sums(&vv, 1);
    if (threadIdx.x == 0) atomicAdd(&SC[sW2b], tot[0]);
  }
}

__global__ void vscale2(float* __restrict__ o1, const float* __restrict__ i1,
                        int s1, int f1, int r1,
                        float* __restrict__ o2, const float* __restrict__ i2,
                        int s2, int f2, int r2, const float* __restrict__ SC) {
  int n = blockIdx.x * 256 + threadIdx.x;
  float v1 = i1[(size_t)n * s1 + f1];
  if (r1 >= 0) v1 *= rsqrtf(SC[r1]);
  o1[n] = v1;
  float v2 = i2[(size_t)n * s2 + f2];
  if (r2 >= 0) v2 *= rsqrtf(SC[r2]);
  o2[n] = v2;
}

__global__ void vscale1(float* __restrict__ out, const float* __restrict__ in,
                        int stride, int off, const float* __restrict__ SC, int rs_idx) {
  int n = blockIdx.x * 256 + threadIdx.x;
  float v = in[(size_t)n * stride + off];
  if (rs_idx >= 0) v *= rsqrtf(SC[rs_idx]);
  out[n] = v;
}

__global__ void axpy_sq(float* __restrict__ out, const float* __restrict__ Y, int stride,
                        int off, const float* __restrict__ q0, const float* __restrict__ q1,
                        const float* __restrict__ q2, float* __restrict__ SC,
                        int c0, int c1, int c2, int np, int coef_rs, int out_rs,
                        int ssq_idx) {
  int n = blockIdx.x * 256 + threadIdx.x;
  float crs = (coef_rs >= 0) ? rsqrtf(SC[coef_rs]) : 1.f;
  float s = Y[(size_t)n * stride + off];
  if (np > 0) s -= SC[c0] * crs * q0[n];
  if (np > 1) s -= SC[c1] * crs * q1[n];
  if (np > 2) s -= SC[c2] * crs * q2[n];
  if (out_rs >= 0) s *= rsqrtf(SC[out_rs]);
  out[n] = s;
  if (ssq_idx >= 0) {
    float v = s * s;
    float* tot = blk_sums(&v, 1);
    if (threadIdx.x == 0) atomicAdd(&SC[ssq_idx], tot[0]);
  }
}

__global__ void accum2b(float* __restrict__ SC, int zA, int nyA, int zB, int nyB) {
  if (threadIdx.x || blockIdx.x) return;
  float add = 0.f;
  for (int k = 0; k < 3; ++k) add += sqrtf(fabsf(SC[zA + k] / SC[nyA + k]));
  for (int k = 0; k < 3; ++k) add += sqrtf(fabsf(SC[zB + k] / SC[nyB + k]));
  SC[5] += add;
}

__global__ void accum2k(float* __restrict__ SC, int zzA, int nt, int nyA,
                        int zzB, int nyB, int dp, int nd) {
  if (threadIdx.x || blockIdx.x) return;
  float vmv = 0.f;
  for (int t = 0; t < nt; ++t) {
    int pc = __popc(t);
    vmv += (pc & 1) ? -SC[zzA + t] : SC[zzA + t];
  }
  float add = sqrtf(fabsf(vmv / SC[nyA]));
  float vb = SC[zzB];
  for (int t = 0; t < nd; ++t) vb -= SC[dp + 2 * t] * SC[dp + 2 * t + 1];
  add += sqrtf(fabsf(vb / SC[nyB]));
  SC[5] += add;
}

__global__ void finalize_k(const float* __restrict__ SC, float* __restrict__ out) {
  if (threadIdx.x || blockIdx.x) return;
  const float Ef = (float)EDG;
  float m1 = SC[0] / Ef, v1 = SC[1] / Ef - m1 * m1;
  float m2 = SC[2] / Ef, v2 = SC[3] / Ef - m2 * m2;
  out[131072] = 0.01f * (v1 + v2) + 0.01f * SC[5];
  out[393217] = SC[4] / (float)N;
}

// ---------------------------------------------------------------------------
extern "C" void kernel_launch(void* const* d_in, const int* in_sizes, int n_in,
                              void* d_out, int out_size, void* d_ws, size_t ws_size,
                              hipStream_t stream) {
  const float* x      = (const float*)d_in[0];
  const int*   ei     = (const int*)  d_in[1];
  const float* gcn1_w = (const float*)d_in[2];
  const float* gcn1_b = (const float*)d_in[3];
  const float* gcn2_w = (const float*)d_in[4];
  const float* gcn2_b = (const float*)d_in[5];
  const float* p1w1   = (const float*)d_in[6];
  const float* p1b1   = (const float*)d_in[7];
  const float* p1w2   = (const float*)d_in[8];
  const float* p1b2   = (const float*)d_in[9];
  const float* p2w1   = (const float*)d_in[10];
  const float* p2b1   = (const float*)d_in[11];
  const float* p2w2   = (const float*)d_in[12];
  const float* p2b2   = (const float*)d_in[13];
  const float* omega1 = (const float*)d_in[14];
  const float* omega2 = (const float*)d_in[15];
  float* out = (float*)d_out;

  float* ws = (float*)d_ws;
  size_t o = 0;
  auto alloc = [&](size_t nf) { float* p = ws + o; o += nf; return p; };
  float* xw1  = alloc((size_t)N * 64);
  float* h1   = alloc((size_t)N * 64);
  float* x1   = alloc((size_t)N * 64);
  float* P    = alloc((size_t)N * 64);
  float* x1w  = alloc((size_t)N * 32);
  float* h2   = alloc((size_t)N * 16);
  float* P2   = alloc((size_t)N * 16);
  float* dis1 = alloc(N);
  float* dis2 = alloc(N);
  float* OmA  = alloc((size_t)N * 8);
  float* OmB  = alloc((size_t)N * 8);
  float* QA   = alloc((size_t)N * 8);
  float* QB   = alloc((size_t)N * 8);
  float* ZA   = alloc((size_t)N * 8);
  float* ZB   = alloc((size_t)N * 8);
  float* BtA  = alloc((size_t)N * 8);
  float* BtB  = alloc((size_t)N * 8);
  float* V8A  = alloc((size_t)N * 8);
  float* V8B  = alloc((size_t)N * 8);
  float* WA   = alloc((size_t)N * 8);
  float* WB   = alloc((size_t)N * 4);
  float* TA   = alloc((size_t)N * 8);
  float* TB   = alloc((size_t)N * 4);
  float* YA   = alloc((size_t)N * 8);
  float* YB   = alloc((size_t)N * 4);
  float* ZZA  = alloc((size_t)N * 8);
  float* ZZB  = alloc((size_t)N * 4);
  float* P4   = alloc((size_t)N * 4);
  float* yvA  = alloc(N);
  float* yvB  = alloc(N);
  float* UvA  = alloc((size_t)3 * N);
  float* UvB  = alloc((size_t)3 * N);
  float* Pv   = alloc((size_t)3 * N);
  float* SMFA = alloc(64);
  float* SMFB = alloc(64);
  int* rowptr = (int*)alloc(2 * (N + 1) + 2);
  int* cur    = (int*)alloc(2 * N);
  int* col_s  = (int*)alloc(EDG);
  int* perm_s = (int*)alloc(EDG);
  int* col_d  = (int*)alloc(EDG);
  int* perm_d = (int*)alloc(EDG);
  float* w1s  = alloc(EDG);
  float* w1d  = alloc(EDG);
  float* w2s  = alloc(EDG);
  float* w2d  = alloc(EDG);
  // zeroed block: Gd (12 slots x 24 doubles) | cnt(2N int) | deg1 | deg2 | SC
  o = (o + 1) & ~(size_t)1;
  float* zb = ws + o;
  double* Gd = (double*)zb;            o += 288 * 2;
  int* cnt   = (int*)(ws + o);         o += 2 * N;
  float* deg1 = alloc(N);
  float* deg2 = alloc(N);
  float* SC   = alloc(1024);
  const size_t zero_bytes = (576 + 2 * N + 2 * N + 1024) * sizeof(float);
  if (ws_size < o * sizeof(float)) return;

  const int* rp_s = rowptr;
  const int* rp_d = rowptr + (N + 1);

  int cs = 8;
  auto NS = [&]() { int s = cs; cs += 8; return s; };
  int gslot = 0;
  auto NG = [&]() { int g = gslot; gslot += 24; return g; };

  // ===================== init + CSR =====================
  hipMemsetAsync(zb, 0, zero_bytes, stream);
  hist_edges<<<512, 256, 0, stream>>>(ei, cnt);
  scan2x<<<2, 256, 0, stream>>>(cnt, rowptr, cur);
  scatter_edges<<<512, 256, 0, stream>>>(ei, cur, col_s, perm_s, col_d, perm_d);

  // ===================== layer 1 =====================
  gemm512<<<256, 256, 0, stream>>>(x, p1w1, gcn1_w, xw1, h1);
  edge_gate1<<<2048, 256, 0, stream>>>(xw1, ei, p1b1, p1w2, p1b2,
                                       out + 131073, deg1, SC + 0);
  gather_w2<<<512, 256, 0, stream>>>(out + 131073, perm_s, perm_d, w1s, w1d);
  make_dis<<<16, 256, 0, stream>>>(deg1, dis1);
  spmm<64, 1><<<1024, 256, 0, stream>>>(rp_d, col_d, w1d, h1, dis1, P, SC, -1, 0.f, -1, -1);
  conv_epi64<<<1024, 256, 0, stream>>>(P, h1, dis1, gcn1_b, x1);

  // ===================== layer 2 + outputs =====================
  gemm64<<<128, 256, 0, stream>>>(x1, p2w1, gcn2_w, x1w, h2);
  edge_gate2<<<1024, 256, 0, stream>>>(x1w, ei, p2b1, p2w2, p2b2,
                                       out + 262145, deg2, SC + 2);
  gather_w2<<<512, 256, 0, stream>>>(out + 262145, perm_s, perm_d, w2s, w2d);
  make_dis<<<16, 256, 0, stream>>>(deg2, dis2);
  spmm<16, 1><<<1024, 256, 0, stream>>>(rp_d, col_d, w2d, h2, dis2, P2, SC, -1, 0.f, -1, -1);
  conv2_softmax<<<16, 256, 0, stream>>>(P2, h2, dis2, gcn2_b, out, out + 65536, SC);

  // ===================== batched SVD (both graphs) =====================
  {
    int s0a = NS(), s0b = NS();
    pad8c2<<<16, 256, 0, stream>>>(omega1, OmA, omega2, OmB, SC, s0a, s0b);
    spmm2<8, 8><<<1024, 256, 0, stream>>>(rp_s, col_s, w1s, w2s, OmA, OmB, QA, QB,
                                          SC, s0a, s0b, GEPS, -1, -1, -1, -1);
    int g0a = NG(), g0b = NG();
    gram2<<<16, 256, 0, stream>>>(QA, QB, Gd + g0a, Gd + g0b);
    int cqa = NS(), cqb = NS();
    chol2<<<16, 256, 0, stream>>>(QA, Gd + g0a, cqa, QB, Gd + g0b, cqb, SC);
    for (int itp = 0; itp < 2; ++itp) {
      spmm2<8, 8><<<1024, 256, 0, stream>>>(rp_d, col_d, w1d, w2d, QA, QB, ZA, ZB,
                                            SC, cqa, cqb, GEPS, -1, -1, -1, -1);
      int gza = NG(), gzb = NG();
      gram2<<<16, 256, 0, stream>>>(ZA, ZB, Gd + gza, Gd + gzb);
      int cza = NS(), czb = NS();
      chol2<<<16, 256, 0, stream>>>(ZA, Gd + gza, cza, ZB, Gd + gzb, czb, SC);
      spmm2<8, 8><<<1024, 256, 0, stream>>>(rp_s, col_s, w1s, w2s, ZA, ZB, QA, QB,
                                            SC, cza, czb, GEPS, -1, -1, -1, -1);
      int gqa = NG(), gqb = NG();
      gram2<<<16, 256, 0, stream>>>(QA, QB, Gd + gqa, Gd + gqb);
      cqa = NS(); cqb = NS();
      chol2<<<16, 256, 0, stream>>>(QA, Gd + gqa, cqa, QB, Gd + gqb, cqb, SC);
    }
    spmm2<8, 8><<<1024, 256, 0, stream>>>(rp_d, col_d, w1d, w2d, QA, QB, BtA, BtB,
                                          SC, cqa, cqb, GEPS, -1, -1, -1, -1);
    int gba = NG(), gbb = NG();
    gram2<<<16, 256, 0, stream>>>(BtA, BtB, Gd + gba, Gd + gbb);
    jacobi2<<<1, 128, 0, stream>>>(Gd + gba, Gd + gbb, SMFA, SMFB);
    v_scale2<<<16, 256, 0, stream>>>(BtA, SMFA, BtB, SMFB, V8A, V8B);
  }

  // ===================== batched batch3 (first 3 sigmas of each graph) =======
  int nyB0;
  {
    int sWa = NS(), sWb = NS();
    pack3c2<<<16, 256, 0, stream>>>(V8A, WA, V8B, WB, SC, sWa, sWb);
    int sTa = NS(), sTb = NS();
    spmm2<4, 4><<<1024, 256, 0, stream>>>(rp_d, col_d, w1d, w2d, WA, WB, TA, TB,
                                          SC, sWa, sWb, GEPS, sTa, -1, sTb, -1);
    int sYa = NS(), sYb = NS(), nyA = NS(), nyB = NS();
    spmm2<4, 4><<<1024, 256, 0, stream>>>(rp_s, col_s, w1s, w2s, TA, TB, YA, YB,
                                          SC, sTa, sTb, GEPS, sYa, nyA, sYb, nyB);
    int zzA = NS(), zzB = NS();
    spmm2<4, 4><<<1024, 256, 0, stream>>>(rp_d, col_d, w1d, w2d, YA, YB, ZZA, ZZB,
                                          SC, sYa, sYb, GEPS, -1, zzA, -1, zzB);
    accum2b<<<1, 1, 0, stream>>>(SC, zzA, nyA, zzB, nyB);
    vscale2<<<16, 256, 0, stream>>>(UvA, YA, 4, 2, nyA + 2,
                                    UvB, YB, 4, 2, nyB + 2, SC);
    nyB0 = nyB;
  }

  // layer-B p0 = A @ (ZZB col2 * rsqrt(nyB+2))
  {
    int sWp = NS();
    build_Wc<<<16, 256, 0, stream>>>(WB, 4, 1, 0, ZZB, 4, 2, nullptr, SC, nyB0 + 2, SC, sWp);
    spmm<4, 0><<<1024, 256, 0, stream>>>(rp_s, col_s, w2s, WB, nullptr, P4, SC, sWp, GEPS, -1, -1);
    vscale1<<<16, 256, 0, stream>>>(Pv, P4, 4, 0, SC, -1);
  }

  // ===================== batched deflation k=3,4,5 =====================
  for (int k = 3; k <= 5; ++k) {
    const int nu = k - 2, nt = 1 << nu, nd = k - 2;
    const int FA = (k < 5) ? 4 : 8;
    int sWa = NS(), sWb = NS(), C = NS(), sTa = NS(), sTb = NS();
    int nyA2 = NS(), nyB2 = NS(), sW2a = NS(), sW2b = NS(), zzA2 = NS(), zzB2 = NS(), dp = NS();
    buildAB<<<32, 256, 0, stream>>>(WA, FA, nt, nu, V8A, k, UvA, SC, sWa,
                                    WB, V8B, UvB, nd, sWb, C);
    if (FA == 4) {
      spmm2<4, 4><<<1024, 256, 0, stream>>>(rp_d, col_d, w1d, w2d, WA, WB, TA, TB,
                                            SC, sWa, sWb, GEPS, sTa, -1, sTb, -1);
      spmm2<4, 4><<<1024, 256, 0, stream>>>(rp_s, col_s, w1s, w2s, TA, TB, YA, YB,
                                            SC, sTa, sTb, GEPS, -1, -1, -1, -1);
    } else {
      spmm2<8, 4><<<1024, 256, 0, stream>>>(rp_d, col_d, w1d, w2d, WA, WB, TA, TB,
                                            SC, sWa, sWb, GEPS, sTa, -1, sTb, -1);
      spmm2<8, 4><<<1024, 256, 0, stream>>>(rp_s, col_s, w1s, w2s, TA, TB, YA, YB,
                                            SC, sTa, sTb, GEPS, -1, -1, -1, -1);
    }
    epiAB<<<32, 256, 0, stream>>>(YA, FA, nt, nu, UvA, yvA, nyA2,
                                  YB, Pv, UvB, nd, yvB, C, nyB2, dp, SC);
    buildAB2<<<32, 256, 0, stream>>>(WA, FA, nt, nu, yvA, UvA, sW2a,
                                     WB, yvB, sW2b, SC);
    if (FA == 4)
      spmm2<4, 4><<<1024, 256, 0, stream>>>(rp_d, col_d, w1d, w2d, WA, WB, ZZA, ZZB,
                                            SC, sW2a, sW2b, GEPS, -1, zzA2, -1, zzB2);
    else
      spmm2<8, 4><<<1024, 256, 0, stream>>>(rp_d, col_d, w1d, w2d, WA, WB, ZZA, ZZB,
                                            SC, sW2a, sW2b, GEPS, -1, zzA2, -1, zzB2);
    accum2k<<<1, 1, 0, stream>>>(SC, zzA2, nt, nyA2, zzB2, nyB2, dp, nd);
    if (k < 5) {
      vscale2<<<16, 256, 0, stream>>>(UvA + (size_t)(k - 2) * N, yvA, 1, 0, nyA2,
                                      UvB + (size_t)(k - 2) * N, yvB, 1, 0, nyB2, SC);
      int sW3 = NS();
      build_Wc<<<16, 256, 0, stream>>>(WB, 4, 1, 0, ZZB, 4, 0, nullptr, SC, nyB2, SC, sW3);
      spmm<4, 0><<<1024, 256, 0, stream>>>(rp_s, col_s, w2s, WB, nullptr, P4, SC, sW3, GEPS, -1, -1);
      axpy_sq<<<16, 256, 0, stream>>>(Pv + (size_t)(k - 2) * N, P4, 4, 0,
                                      Pv, Pv + N, Pv + 2 * N,
                                      SC, dp + 1, dp + 3, dp + 5, nd, nyB2, -1, -1);
    }
  }

  finalize_k<<<1, 1, 0, stream>>>(SC, out);
}